// Round 3
// baseline (4032.149 us; speedup 1.0000x reference)
//
#include <hip/hip_runtime.h>
#include <math.h>

// EdgeNetEMD: BatchNorm(4) -> EdgeConv(8->32->32->2, relu_last) -> EdgeConv(4->32->32->4)
// N=100000 nodes, E=3200000 edges, fp32.
// Round 3: CSR-gather design, scan aliasing bug fixed (separate bsum/bbase +
// temp read-before-write). One atomic pass (rank_hist); MLP aggregation is
// atomic-free register accumulation, one thread per node.

constexpr int DD  = 4;   // node feature dim
constexpr int BIG = 32;  // hidden dim
constexpr int HID = 2;   // encoder output dim

// ---------------- BatchNorm statistics ----------------
__global__ void bn_reduce_kernel(const float* __restrict__ x, int n,
                                 float* __restrict__ sums /* [8]: sum4, sumsq4 */)
{
    float s0=0.f,s1=0.f,s2=0.f,s3=0.f,q0=0.f,q1=0.f,q2=0.f,q3=0.f;
    int stride = gridDim.x * blockDim.x;
    for (int i = blockIdx.x * blockDim.x + threadIdx.x; i < n; i += stride) {
        float4 v = reinterpret_cast<const float4*>(x)[i];
        s0 += v.x; s1 += v.y; s2 += v.z; s3 += v.w;
        q0 = fmaf(v.x, v.x, q0); q1 = fmaf(v.y, v.y, q1);
        q2 = fmaf(v.z, v.z, q2); q3 = fmaf(v.w, v.w, q3);
    }
    #pragma unroll
    for (int off = 32; off >= 1; off >>= 1) {
        s0 += __shfl_down(s0, off); s1 += __shfl_down(s1, off);
        s2 += __shfl_down(s2, off); s3 += __shfl_down(s3, off);
        q0 += __shfl_down(q0, off); q1 += __shfl_down(q1, off);
        q2 += __shfl_down(q2, off); q3 += __shfl_down(q3, off);
    }
    __shared__ float red[4][8];
    int wave = threadIdx.x >> 6;
    int lane = threadIdx.x & 63;
    if (lane == 0) {
        red[wave][0]=s0; red[wave][1]=s1; red[wave][2]=s2; red[wave][3]=s3;
        red[wave][4]=q0; red[wave][5]=q1; red[wave][6]=q2; red[wave][7]=q3;
    }
    __syncthreads();
    if (threadIdx.x < 8) {
        int nw = blockDim.x >> 6;
        float t = 0.f;
        for (int w = 0; w < nw; ++w) t += red[w][threadIdx.x];
        atomicAdd(&sums[threadIdx.x], t);
    }
}

__global__ void bn_finalize_kernel(const float* __restrict__ sums,
                                   const float* __restrict__ gamma,
                                   const float* __restrict__ beta,
                                   float* __restrict__ ab, float invN)
{
    int f = threadIdx.x;
    if (f < DD) {
        float mean = sums[f] * invN;
        float var  = sums[DD + f] * invN - mean * mean;
        float a = gamma[f] / sqrtf(var + 1e-5f);
        ab[f]      = a;
        ab[DD + f] = beta[f] - mean * a;
    }
}

// ---------------- CSR construction ----------------
__global__ __launch_bounds__(256) void rank_hist_kernel(const int* __restrict__ dst, int E,
                                                        int* __restrict__ deg,
                                                        unsigned short* __restrict__ rank)
{
    int e = blockIdx.x * 256 + threadIdx.x;
    if (e >= E) return;
    int d = dst[e];
    int old = atomicAdd(&deg[d], 1);
    rank[e] = (unsigned short)old;
}

constexpr int SCAN_CHUNK = 1024;  // elems per block (256 thr x 4)

__global__ __launch_bounds__(256) void scan_block_sums_kernel(const int* __restrict__ deg, int n,
                                                              int* __restrict__ bsum)
{
    int b = blockIdx.x;
    int base = b * SCAN_CHUNK + threadIdx.x * 4;
    int s = 0;
    #pragma unroll
    for (int k = 0; k < 4; ++k) { int i = base + k; if (i < n) s += deg[i]; }
    #pragma unroll
    for (int o = 32; o >= 1; o >>= 1) s += __shfl_down(s, o);
    __shared__ int red[4];
    int wave = threadIdx.x >> 6, lane = threadIdx.x & 63;
    if (lane == 0) red[wave] = s;
    __syncthreads();
    if (threadIdx.x == 0) bsum[b] = red[0] + red[1] + red[2] + red[3];
}

// NOTE: bsum and bbase are SEPARATE buffers (round-2 bug: aliased in-place
// exclusive scan did write-then-read on the same address -> garbage bases ->
// unwritten ssrc -> wild gather -> GPU memory fault).
__global__ void scan_base_kernel(const int* bsum, int nb, int* bbase)
{
    if (threadIdx.x == 0) {
        int running = 0;
        for (int b = 0; b < nb; ++b) {
            int v = bsum[b];       // read BEFORE any write
            bbase[b] = running;
            running += v;
        }
    }
}

__global__ __launch_bounds__(256) void scan_write_kernel(const int* __restrict__ deg, int n,
                                                         const int* __restrict__ bbase,
                                                         int* __restrict__ off)
{
    int b = blockIdx.x, tid = threadIdx.x;
    int base = b * SCAN_CHUNK + tid * 4;
    int v[4]; int s = 0;
    #pragma unroll
    for (int k = 0; k < 4; ++k) { int i = base + k; v[k] = (i < n) ? deg[i] : 0; s += v[k]; }
    int lane = tid & 63, wave = tid >> 6;
    int inc = s;
    #pragma unroll
    for (int o = 1; o < 64; o <<= 1) { int t = __shfl_up(inc, o); if (lane >= o) inc += t; }
    __shared__ int wsum[4];
    if (lane == 63) wsum[wave] = inc;
    __syncthreads();
    int wbase = 0;
    for (int w = 0; w < wave; ++w) wbase += wsum[w];
    int cur = bbase[b] + wbase + inc - s;   // exclusive prefix for this thread
    #pragma unroll
    for (int k = 0; k < 4; ++k) {
        int i = base + k;
        if (i < n) {
            off[i] = cur;
            cur += v[k];
            if (i == n - 1) off[n] = cur;
        }
    }
}

__global__ __launch_bounds__(256) void scatter_kernel(const int* __restrict__ src,
                                                      const int* __restrict__ dst,
                                                      const unsigned short* __restrict__ rank,
                                                      const int* __restrict__ off,
                                                      int* __restrict__ ssrc, int E)
{
    int e = blockIdx.x * 256 + threadIdx.x;
    if (e >= E) return;
    int d = dst[e];
    int idx = off[d] + (int)rank[e];
    idx = min(max(idx, 0), E - 1);   // safety clamp (fault -> wrong value, not crash)
    ssrc[idx] = src[e];
}

// ---------------- Encoder gather: per node, in 8 -> 32 -> 32 -> 2 (relu) ----------------
__global__ __launch_bounds__(256) void enc_gather_kernel(
    const float* __restrict__ x, const int* __restrict__ ssrc, const int* __restrict__ off,
    const float* __restrict__ ab,
    const float* __restrict__ W1, const float* __restrict__ b1,
    const float* __restrict__ W2, const float* __restrict__ b2,
    const float* __restrict__ W3, const float* __restrict__ b3,
    float* __restrict__ h1, int N)
{
    int i = blockIdx.x * 256 + threadIdx.x;
    if (i >= N) return;
    float4 xi = reinterpret_cast<const float4*>(x)[i];
    float a0 = ab[0], a1 = ab[1], a2 = ab[2], a3 = ab[3];
    float c0 = ab[4], c1 = ab[5], c2 = ab[6], c3 = ab[7];
    float n0 = fmaf(xi.x, a0, c0), n1 = fmaf(xi.y, a1, c1);
    float n2 = fmaf(xi.z, a2, c2), n3 = fmaf(xi.w, a3, c3);

    // loop-invariant half of layer 1
    float base1[BIG];
    #pragma unroll
    for (int j = 0; j < BIG; ++j) {
        float t = b1[j];
        t = fmaf(n0, W1[0 * BIG + j], t);
        t = fmaf(n1, W1[1 * BIG + j], t);
        t = fmaf(n2, W1[2 * BIG + j], t);
        t = fmaf(n3, W1[3 * BIG + j], t);
        base1[j] = t;
    }

    int beg = off[i], end = off[i + 1];
    float acc0 = 0.f, acc1 = 0.f;
    for (int p = beg; p < end; ++p) {
        int s = ssrc[p];
        s = min(max(s, 0), N - 1);   // safety clamp
        float4 xs = reinterpret_cast<const float4*>(x)[s];
        float d0 = (xs.x - xi.x) * a0;
        float d1 = (xs.y - xi.y) * a1;
        float d2 = (xs.z - xi.z) * a2;
        float d3 = (xs.w - xi.w) * a3;

        float h[BIG];
        #pragma unroll
        for (int j = 0; j < BIG; ++j) {
            float t = base1[j];
            t = fmaf(d0, W1[4 * BIG + j], t);
            t = fmaf(d1, W1[5 * BIG + j], t);
            t = fmaf(d2, W1[6 * BIG + j], t);
            t = fmaf(d3, W1[7 * BIG + j], t);
            h[j] = fmaxf(t, 0.0f);
        }
        float g[BIG];
        #pragma unroll
        for (int j = 0; j < BIG; ++j) {
            float t = b2[j];
            #pragma unroll
            for (int k = 0; k < BIG; ++k) t = fmaf(h[k], W2[k * BIG + j], t);
            g[j] = fmaxf(t, 0.0f);
        }
        float u0 = b3[0], u1 = b3[1];
        #pragma unroll
        for (int k = 0; k < BIG; ++k) {
            u0 = fmaf(g[k], W3[k * HID + 0], u0);
            u1 = fmaf(g[k], W3[k * HID + 1], u1);
        }
        acc0 += fmaxf(u0, 0.0f);
        acc1 += fmaxf(u1, 0.0f);
    }
    float inv = 1.0f / fmaxf((float)(end - beg), 1.0f);
    h1[i * HID + 0] = acc0 * inv;
    h1[i * HID + 1] = acc1 * inv;
}

// ---------------- Decoder gather: per node, in 4 -> 32 -> 32 -> 4 ----------------
__global__ __launch_bounds__(256) void dec_gather_kernel(
    const float* __restrict__ h1, const int* __restrict__ ssrc, const int* __restrict__ off,
    const float* __restrict__ W1, const float* __restrict__ b1,
    const float* __restrict__ W2, const float* __restrict__ b2,
    const float* __restrict__ W3, const float* __restrict__ b3,
    float* __restrict__ out, int N)
{
    int i = blockIdx.x * 256 + threadIdx.x;
    if (i >= N) return;
    float2 hd = reinterpret_cast<const float2*>(h1)[i];

    float base1[BIG];
    #pragma unroll
    for (int j = 0; j < BIG; ++j) {
        float t = b1[j];
        t = fmaf(hd.x, W1[0 * BIG + j], t);
        t = fmaf(hd.y, W1[1 * BIG + j], t);
        base1[j] = t;
    }

    int beg = off[i], end = off[i + 1];
    float acc0 = 0.f, acc1 = 0.f, acc2 = 0.f, acc3 = 0.f;
    for (int p = beg; p < end; ++p) {
        int s = ssrc[p];
        s = min(max(s, 0), N - 1);   // safety clamp
        float2 hs = reinterpret_cast<const float2*>(h1)[s];
        float d0 = hs.x - hd.x;
        float d1 = hs.y - hd.y;

        float h[BIG];
        #pragma unroll
        for (int j = 0; j < BIG; ++j) {
            float t = base1[j];
            t = fmaf(d0, W1[2 * BIG + j], t);
            t = fmaf(d1, W1[3 * BIG + j], t);
            h[j] = fmaxf(t, 0.0f);
        }
        float g[BIG];
        #pragma unroll
        for (int j = 0; j < BIG; ++j) {
            float t = b2[j];
            #pragma unroll
            for (int k = 0; k < BIG; ++k) t = fmaf(h[k], W2[k * BIG + j], t);
            g[j] = fmaxf(t, 0.0f);
        }
        float u0 = b3[0], u1 = b3[1], u2 = b3[2], u3 = b3[3];
        #pragma unroll
        for (int k = 0; k < BIG; ++k) {
            u0 = fmaf(g[k], W3[k * DD + 0], u0);
            u1 = fmaf(g[k], W3[k * DD + 1], u1);
            u2 = fmaf(g[k], W3[k * DD + 2], u2);
            u3 = fmaf(g[k], W3[k * DD + 3], u3);
        }
        acc0 += u0; acc1 += u1; acc2 += u2; acc3 += u3;
    }
    float inv = 1.0f / fmaxf((float)(end - beg), 1.0f);
    float4 o;
    o.x = acc0 * inv; o.y = acc1 * inv; o.z = acc2 * inv; o.w = acc3 * inv;
    reinterpret_cast<float4*>(out)[i] = o;
}

// ---------------- Fallback (round-1 atomic path) ----------------
__global__ __launch_bounds__(256) void enc_edge_kernel(
    const float* __restrict__ x, const int* __restrict__ src, const int* __restrict__ dst,
    const float* __restrict__ ab,
    const float* __restrict__ W1, const float* __restrict__ b1,
    const float* __restrict__ W2, const float* __restrict__ b2,
    const float* __restrict__ W3, const float* __restrict__ b3,
    float* __restrict__ acc, float* __restrict__ cnt, int E)
{
    int e = blockIdx.x * blockDim.x + threadIdx.x;
    if (e >= E) return;
    int si = src[e];
    int di = dst[e];
    float4 xd = reinterpret_cast<const float4*>(x)[di];
    float4 xs = reinterpret_cast<const float4*>(x)[si];
    float a0 = ab[0], a1 = ab[1], a2 = ab[2], a3 = ab[3];
    float c0 = ab[4], c1 = ab[5], c2 = ab[6], c3 = ab[7];
    float in[2 * DD];
    in[0] = fmaf(xd.x, a0, c0); in[1] = fmaf(xd.y, a1, c1);
    in[2] = fmaf(xd.z, a2, c2); in[3] = fmaf(xd.w, a3, c3);
    in[4] = (xs.x - xd.x) * a0; in[5] = (xs.y - xd.y) * a1;
    in[6] = (xs.z - xd.z) * a2; in[7] = (xs.w - xd.w) * a3;
    float h[BIG];
    #pragma unroll
    for (int j = 0; j < BIG; ++j) {
        float t = b1[j];
        #pragma unroll
        for (int k = 0; k < 2 * DD; ++k) t = fmaf(in[k], W1[k * BIG + j], t);
        h[j] = fmaxf(t, 0.0f);
    }
    float g[BIG];
    #pragma unroll
    for (int j = 0; j < BIG; ++j) {
        float t = b2[j];
        #pragma unroll
        for (int k = 0; k < BIG; ++k) t = fmaf(h[k], W2[k * BIG + j], t);
        g[j] = fmaxf(t, 0.0f);
    }
    float u0 = b3[0], u1 = b3[1];
    #pragma unroll
    for (int k = 0; k < BIG; ++k) {
        u0 = fmaf(g[k], W3[k * HID + 0], u0);
        u1 = fmaf(g[k], W3[k * HID + 1], u1);
    }
    atomicAdd(&acc[di * HID + 0], fmaxf(u0, 0.0f));
    atomicAdd(&acc[di * HID + 1], fmaxf(u1, 0.0f));
    atomicAdd(&cnt[di], 1.0f);
}

__global__ void finalize_h1_kernel(float* __restrict__ acc, const float* __restrict__ cnt, int n)
{
    int i = blockIdx.x * blockDim.x + threadIdx.x;
    if (i >= n) return;
    float inv = 1.0f / fmaxf(cnt[i], 1.0f);
    acc[i * HID + 0] *= inv;
    acc[i * HID + 1] *= inv;
}

__global__ __launch_bounds__(256) void dec_edge_kernel(
    const float* __restrict__ h1, const int* __restrict__ src, const int* __restrict__ dst,
    const float* __restrict__ W1, const float* __restrict__ b1,
    const float* __restrict__ W2, const float* __restrict__ b2,
    const float* __restrict__ W3, const float* __restrict__ b3,
    float* __restrict__ out, int E)
{
    int e = blockIdx.x * blockDim.x + threadIdx.x;
    if (e >= E) return;
    int si = src[e];
    int di = dst[e];
    float2 hd = reinterpret_cast<const float2*>(h1)[di];
    float2 hs = reinterpret_cast<const float2*>(h1)[si];
    float in[2 * HID];
    in[0] = hd.x; in[1] = hd.y;
    in[2] = hs.x - hd.x; in[3] = hs.y - hd.y;
    float h[BIG];
    #pragma unroll
    for (int j = 0; j < BIG; ++j) {
        float t = b1[j];
        #pragma unroll
        for (int k = 0; k < 2 * HID; ++k) t = fmaf(in[k], W1[k * BIG + j], t);
        h[j] = fmaxf(t, 0.0f);
    }
    float g[BIG];
    #pragma unroll
    for (int j = 0; j < BIG; ++j) {
        float t = b2[j];
        #pragma unroll
        for (int k = 0; k < BIG; ++k) t = fmaf(h[k], W2[k * BIG + j], t);
        g[j] = fmaxf(t, 0.0f);
    }
    float u0 = b3[0], u1 = b3[1], u2 = b3[2], u3 = b3[3];
    #pragma unroll
    for (int k = 0; k < BIG; ++k) {
        u0 = fmaf(g[k], W3[k * DD + 0], u0);
        u1 = fmaf(g[k], W3[k * DD + 1], u1);
        u2 = fmaf(g[k], W3[k * DD + 2], u2);
        u3 = fmaf(g[k], W3[k * DD + 3], u3);
    }
    atomicAdd(&out[di * DD + 0], u0);
    atomicAdd(&out[di * DD + 1], u1);
    atomicAdd(&out[di * DD + 2], u2);
    atomicAdd(&out[di * DD + 3], u3);
}

__global__ void finalize_out_kernel(float* __restrict__ out, const float* __restrict__ cnt, int n)
{
    int i = blockIdx.x * blockDim.x + threadIdx.x;
    if (i >= n) return;
    float inv = 1.0f / fmaxf(cnt[i], 1.0f);
    float4 v = reinterpret_cast<float4*>(out)[i];
    v.x *= inv; v.y *= inv; v.z *= inv; v.w *= inv;
    reinterpret_cast<float4*>(out)[i] = v;
}

// ---------------- launch ----------------
extern "C" void kernel_launch(void* const* d_in, const int* in_sizes, int n_in,
                              void* d_out, int out_size, void* d_ws, size_t ws_size,
                              hipStream_t stream)
{
    const float* x     = (const float*)d_in[0];
    const int*   src   = (const int*)  d_in[1];
    const int*   dst   = (const int*)  d_in[2];
    const float* gamma = (const float*)d_in[3];
    const float* beta  = (const float*)d_in[4];
    const float* eW1 = (const float*)d_in[5];  const float* eb1 = (const float*)d_in[6];
    const float* eW2 = (const float*)d_in[7];  const float* eb2 = (const float*)d_in[8];
    const float* eW3 = (const float*)d_in[9];  const float* eb3 = (const float*)d_in[10];
    const float* dW1 = (const float*)d_in[11]; const float* db1 = (const float*)d_in[12];
    const float* dW2 = (const float*)d_in[13]; const float* db2 = (const float*)d_in[14];
    const float* dW3 = (const float*)d_in[15]; const float* db3 = (const float*)d_in[16];

    const int N = in_sizes[0] / DD;
    const int E = in_sizes[1];
    float* out = (float*)d_out;

    // workspace layout (CSR path)
    auto rnd16 = [](size_t b) { return (b + 15) & ~(size_t)15; };
    size_t need = 0;
    size_t o_sums  = need; need += rnd16(8 * 4);
    size_t o_ab    = need; need += rnd16(8 * 4);
    size_t o_bsum  = need; need += rnd16(256 * 4);
    size_t o_bbase = need; need += rnd16(256 * 4);
    size_t o_deg   = need; need += rnd16((size_t)N * 4);
    size_t o_off   = need; need += rnd16((size_t)(N + 1) * 4);
    size_t o_rank  = need; need += rnd16((size_t)E * 2);
    size_t o_ssrc  = need; need += rnd16((size_t)E * 4);
    size_t o_h1    = need; need += rnd16((size_t)2 * N * 4);

    char* wsb = (char*)d_ws;

    if (ws_size >= need && N > 0 && E > 0) {
        float*          sums  = (float*)(wsb + o_sums);
        float*          ab    = (float*)(wsb + o_ab);
        int*            bsum  = (int*)  (wsb + o_bsum);
        int*            bbase = (int*)  (wsb + o_bbase);
        int*            deg   = (int*)  (wsb + o_deg);
        int*            off   = (int*)  (wsb + o_off);
        unsigned short* rank  = (unsigned short*)(wsb + o_rank);
        int*            ssrc  = (int*)  (wsb + o_ssrc);
        float*          h1    = (float*)(wsb + o_h1);

        hipMemsetAsync(sums, 0, 8 * sizeof(float), stream);
        hipMemsetAsync(deg, 0, (size_t)N * sizeof(int), stream);

        bn_reduce_kernel<<<256, 256, 0, stream>>>(x, N, sums);
        bn_finalize_kernel<<<1, 64, 0, stream>>>(sums, gamma, beta, ab, 1.0f / (float)N);

        int eblocks = (E + 255) / 256;
        rank_hist_kernel<<<eblocks, 256, 0, stream>>>(dst, E, deg, rank);

        int nb = (N + SCAN_CHUNK - 1) / SCAN_CHUNK;  // 98 blocks for N=100000 (<=256)
        scan_block_sums_kernel<<<nb, 256, 0, stream>>>(deg, N, bsum);
        scan_base_kernel<<<1, 64, 0, stream>>>(bsum, nb, bbase);
        scan_write_kernel<<<nb, 256, 0, stream>>>(deg, N, bbase, off);

        scatter_kernel<<<eblocks, 256, 0, stream>>>(src, dst, rank, off, ssrc, E);

        int nblocks = (N + 255) / 256;
        enc_gather_kernel<<<nblocks, 256, 0, stream>>>(x, ssrc, off, ab,
                                                       eW1, eb1, eW2, eb2, eW3, eb3, h1, N);
        dec_gather_kernel<<<nblocks, 256, 0, stream>>>(h1, ssrc, off,
                                                       dW1, db1, dW2, db2, dW3, db3, out, N);
    } else {
        // fallback: round-1 atomic path (needs only (16+3N) floats)
        float* ws   = (float*)d_ws;
        float* sums = ws;
        float* ab   = ws + 8;
        float* cnt  = ws + 16;
        float* acc1 = ws + 16 + N;

        hipMemsetAsync(sums, 0, 16 * sizeof(float), stream);
        hipMemsetAsync(cnt, 0, (size_t)(3 * N) * sizeof(float), stream);
        hipMemsetAsync(out, 0, (size_t)out_size * sizeof(float), stream);

        bn_reduce_kernel<<<256, 256, 0, stream>>>(x, N, sums);
        bn_finalize_kernel<<<1, 64, 0, stream>>>(sums, gamma, beta, ab, 1.0f / (float)N);

        int eblocks = (E + 255) / 256;
        enc_edge_kernel<<<eblocks, 256, 0, stream>>>(x, src, dst, ab,
                                                     eW1, eb1, eW2, eb2, eW3, eb3,
                                                     acc1, cnt, E);
        finalize_h1_kernel<<<(N + 255) / 256, 256, 0, stream>>>(acc1, cnt, N);
        dec_edge_kernel<<<eblocks, 256, 0, stream>>>(acc1, src, dst,
                                                     dW1, db1, dW2, db2, dW3, db3,
                                                     out, E);
        finalize_out_kernel<<<(N + 255) / 256, 256, 0, stream>>>(out, cnt, N);
    }
}

// Round 4
// 571.124 us; speedup vs baseline: 7.0600x; 7.0600x over previous
//
#include <hip/hip_runtime.h>
#include <math.h>

// EdgeNetEMD: BatchNorm(4) -> EdgeConv(8->32->32->2, relu_last) -> EdgeConv(4->32->32->4)
// N=100000 nodes, E=3200000 edges, fp32.
// Round 4: CSR for atomic-free aggregation, but MLP runs per-EDGE (3.2M threads)
// writing per-edge outputs coalesced; per-node segment reduce afterwards.
// Round-3 failure mode: per-node MLP -> 9.8% occupancy + degree-divergence.

constexpr int DD  = 4;   // node feature dim
constexpr int BIG = 32;  // hidden dim
constexpr int HID = 2;   // encoder output dim

// ---------------- BatchNorm statistics ----------------
__global__ void bn_reduce_kernel(const float* __restrict__ x, int n,
                                 float* __restrict__ sums /* [8]: sum4, sumsq4 */)
{
    float s0=0.f,s1=0.f,s2=0.f,s3=0.f,q0=0.f,q1=0.f,q2=0.f,q3=0.f;
    int stride = gridDim.x * blockDim.x;
    for (int i = blockIdx.x * blockDim.x + threadIdx.x; i < n; i += stride) {
        float4 v = reinterpret_cast<const float4*>(x)[i];
        s0 += v.x; s1 += v.y; s2 += v.z; s3 += v.w;
        q0 = fmaf(v.x, v.x, q0); q1 = fmaf(v.y, v.y, q1);
        q2 = fmaf(v.z, v.z, q2); q3 = fmaf(v.w, v.w, q3);
    }
    #pragma unroll
    for (int off = 32; off >= 1; off >>= 1) {
        s0 += __shfl_down(s0, off); s1 += __shfl_down(s1, off);
        s2 += __shfl_down(s2, off); s3 += __shfl_down(s3, off);
        q0 += __shfl_down(q0, off); q1 += __shfl_down(q1, off);
        q2 += __shfl_down(q2, off); q3 += __shfl_down(q3, off);
    }
    __shared__ float red[4][8];
    int wave = threadIdx.x >> 6;
    int lane = threadIdx.x & 63;
    if (lane == 0) {
        red[wave][0]=s0; red[wave][1]=s1; red[wave][2]=s2; red[wave][3]=s3;
        red[wave][4]=q0; red[wave][5]=q1; red[wave][6]=q2; red[wave][7]=q3;
    }
    __syncthreads();
    if (threadIdx.x < 8) {
        int nw = blockDim.x >> 6;
        float t = 0.f;
        for (int w = 0; w < nw; ++w) t += red[w][threadIdx.x];
        atomicAdd(&sums[threadIdx.x], t);
    }
}

__global__ void bn_finalize_kernel(const float* __restrict__ sums,
                                   const float* __restrict__ gamma,
                                   const float* __restrict__ beta,
                                   float* __restrict__ ab, float invN)
{
    int f = threadIdx.x;
    if (f < DD) {
        float mean = sums[f] * invN;
        float var  = sums[DD + f] * invN - mean * mean;
        float a = gamma[f] / sqrtf(var + 1e-5f);
        ab[f]      = a;
        ab[DD + f] = beta[f] - mean * a;
    }
}

// ---------------- CSR construction ----------------
__global__ __launch_bounds__(256) void rank_hist_kernel(const int* __restrict__ dst, int E,
                                                        int* __restrict__ deg,
                                                        unsigned short* __restrict__ rank)
{
    int e = blockIdx.x * 256 + threadIdx.x;
    if (e >= E) return;
    int d = dst[e];
    int old = atomicAdd(&deg[d], 1);
    rank[e] = (unsigned short)old;
}

constexpr int SCAN_CHUNK = 1024;  // elems per block (256 thr x 4)

__global__ __launch_bounds__(256) void scan_block_sums_kernel(const int* __restrict__ deg, int n,
                                                              int* __restrict__ bsum)
{
    int b = blockIdx.x;
    int base = b * SCAN_CHUNK + threadIdx.x * 4;
    int s = 0;
    #pragma unroll
    for (int k = 0; k < 4; ++k) { int i = base + k; if (i < n) s += deg[i]; }
    #pragma unroll
    for (int o = 32; o >= 1; o >>= 1) s += __shfl_down(s, o);
    __shared__ int red[4];
    int wave = threadIdx.x >> 6, lane = threadIdx.x & 63;
    if (lane == 0) red[wave] = s;
    __syncthreads();
    if (threadIdx.x == 0) bsum[b] = red[0] + red[1] + red[2] + red[3];
}

// bsum and bbase MUST be separate buffers (round-2 aliasing fault).
__global__ void scan_base_kernel(const int* bsum, int nb, int* bbase)
{
    if (threadIdx.x == 0) {
        int running = 0;
        for (int b = 0; b < nb; ++b) {
            int v = bsum[b];       // read BEFORE any write
            bbase[b] = running;
            running += v;
        }
    }
}

__global__ __launch_bounds__(256) void scan_write_kernel(const int* __restrict__ deg, int n,
                                                         const int* __restrict__ bbase,
                                                         int* __restrict__ off)
{
    int b = blockIdx.x, tid = threadIdx.x;
    int base = b * SCAN_CHUNK + tid * 4;
    int v[4]; int s = 0;
    #pragma unroll
    for (int k = 0; k < 4; ++k) { int i = base + k; v[k] = (i < n) ? deg[i] : 0; s += v[k]; }
    int lane = tid & 63, wave = tid >> 6;
    int inc = s;
    #pragma unroll
    for (int o = 1; o < 64; o <<= 1) { int t = __shfl_up(inc, o); if (lane >= o) inc += t; }
    __shared__ int wsum[4];
    if (lane == 63) wsum[wave] = inc;
    __syncthreads();
    int wbase = 0;
    for (int w = 0; w < wave; ++w) wbase += wsum[w];
    int cur = bbase[b] + wbase + inc - s;   // exclusive prefix for this thread
    #pragma unroll
    for (int k = 0; k < 4; ++k) {
        int i = base + k;
        if (i < n) {
            off[i] = cur;
            cur += v[k];
            if (i == n - 1) off[n] = cur;
        }
    }
}

// perm[off[d] + rank[e]] = e  (CSR-ordered edge ids)
__global__ __launch_bounds__(256) void scatter_perm_kernel(const int* __restrict__ dst,
                                                           const unsigned short* __restrict__ rank,
                                                           const int* __restrict__ off,
                                                           int* __restrict__ perm, int E)
{
    int e = blockIdx.x * 256 + threadIdx.x;
    if (e >= E) return;
    int d = dst[e];
    int idx = off[d] + (int)rank[e];
    idx = min(max(idx, 0), E - 1);   // safety clamp (wrong value beats a fault)
    perm[idx] = e;
}

// ---------------- Encoder per-edge MLP: 8 -> 32 -> 32 -> 2 (relu), edge order ----------------
__global__ __launch_bounds__(256) void enc_mlp_kernel(
    const float* __restrict__ x, const int* __restrict__ src, const int* __restrict__ dst,
    const float* __restrict__ ab,
    const float* __restrict__ W1, const float* __restrict__ b1,
    const float* __restrict__ W2, const float* __restrict__ b2,
    const float* __restrict__ W3, const float* __restrict__ b3,
    float2* __restrict__ u, int E)
{
    int e = blockIdx.x * 256 + threadIdx.x;
    if (e >= E) return;
    int si = src[e];
    int di = dst[e];
    float4 xd = reinterpret_cast<const float4*>(x)[di];
    float4 xs = reinterpret_cast<const float4*>(x)[si];
    float a0 = ab[0], a1 = ab[1], a2 = ab[2], a3 = ab[3];
    float c0 = ab[4], c1 = ab[5], c2 = ab[6], c3 = ab[7];

    float in[2 * DD];
    in[0] = fmaf(xd.x, a0, c0);
    in[1] = fmaf(xd.y, a1, c1);
    in[2] = fmaf(xd.z, a2, c2);
    in[3] = fmaf(xd.w, a3, c3);
    in[4] = (xs.x - xd.x) * a0;
    in[5] = (xs.y - xd.y) * a1;
    in[6] = (xs.z - xd.z) * a2;
    in[7] = (xs.w - xd.w) * a3;

    float h[BIG];
    #pragma unroll
    for (int j = 0; j < BIG; ++j) {
        float t = b1[j];
        #pragma unroll
        for (int k = 0; k < 2 * DD; ++k) t = fmaf(in[k], W1[k * BIG + j], t);
        h[j] = fmaxf(t, 0.0f);
    }
    float g[BIG];
    #pragma unroll
    for (int j = 0; j < BIG; ++j) {
        float t = b2[j];
        #pragma unroll
        for (int k = 0; k < BIG; ++k) t = fmaf(h[k], W2[k * BIG + j], t);
        g[j] = fmaxf(t, 0.0f);
    }
    float u0 = b3[0], u1 = b3[1];
    #pragma unroll
    for (int k = 0; k < BIG; ++k) {
        u0 = fmaf(g[k], W3[k * HID + 0], u0);
        u1 = fmaf(g[k], W3[k * HID + 1], u1);
    }
    float2 o;
    o.x = fmaxf(u0, 0.0f);
    o.y = fmaxf(u1, 0.0f);
    u[e] = o;   // coalesced, no atomics
}

// per-node segment mean of u -> h1
__global__ __launch_bounds__(256) void enc_reduce_kernel(
    const float2* __restrict__ u, const int* __restrict__ perm, const int* __restrict__ off,
    float* __restrict__ h1, int N, int E)
{
    int i = blockIdx.x * 256 + threadIdx.x;
    if (i >= N) return;
    int beg = off[i], end = off[i + 1];
    float acc0 = 0.f, acc1 = 0.f;
    for (int p = beg; p < end; ++p) {
        int e = perm[p];
        e = min(max(e, 0), E - 1);
        float2 t = u[e];
        acc0 += t.x; acc1 += t.y;
    }
    float inv = 1.0f / fmaxf((float)(end - beg), 1.0f);
    float2 o; o.x = acc0 * inv; o.y = acc1 * inv;
    reinterpret_cast<float2*>(h1)[i] = o;
}

// ---------------- Decoder per-edge MLP: 4 -> 32 -> 32 -> 4, edge order ----------------
__global__ __launch_bounds__(256) void dec_mlp_kernel(
    const float* __restrict__ h1, const int* __restrict__ src, const int* __restrict__ dst,
    const float* __restrict__ W1, const float* __restrict__ b1,
    const float* __restrict__ W2, const float* __restrict__ b2,
    const float* __restrict__ W3, const float* __restrict__ b3,
    float4* __restrict__ v, int E)
{
    int e = blockIdx.x * 256 + threadIdx.x;
    if (e >= E) return;
    int si = src[e];
    int di = dst[e];
    float2 hd = reinterpret_cast<const float2*>(h1)[di];
    float2 hs = reinterpret_cast<const float2*>(h1)[si];

    float in[2 * HID];
    in[0] = hd.x;
    in[1] = hd.y;
    in[2] = hs.x - hd.x;
    in[3] = hs.y - hd.y;

    float h[BIG];
    #pragma unroll
    for (int j = 0; j < BIG; ++j) {
        float t = b1[j];
        #pragma unroll
        for (int k = 0; k < 2 * HID; ++k) t = fmaf(in[k], W1[k * BIG + j], t);
        h[j] = fmaxf(t, 0.0f);
    }
    float g[BIG];
    #pragma unroll
    for (int j = 0; j < BIG; ++j) {
        float t = b2[j];
        #pragma unroll
        for (int k = 0; k < BIG; ++k) t = fmaf(h[k], W2[k * BIG + j], t);
        g[j] = fmaxf(t, 0.0f);
    }
    float u0 = b3[0], u1 = b3[1], u2 = b3[2], u3 = b3[3];
    #pragma unroll
    for (int k = 0; k < BIG; ++k) {
        u0 = fmaf(g[k], W3[k * DD + 0], u0);
        u1 = fmaf(g[k], W3[k * DD + 1], u1);
        u2 = fmaf(g[k], W3[k * DD + 2], u2);
        u3 = fmaf(g[k], W3[k * DD + 3], u3);
    }
    float4 o; o.x = u0; o.y = u1; o.z = u2; o.w = u3;
    v[e] = o;   // coalesced, no atomics
}

// per-node segment mean of v -> out
__global__ __launch_bounds__(256) void dec_reduce_kernel(
    const float4* __restrict__ v, const int* __restrict__ perm, const int* __restrict__ off,
    float* __restrict__ out, int N, int E)
{
    int i = blockIdx.x * 256 + threadIdx.x;
    if (i >= N) return;
    int beg = off[i], end = off[i + 1];
    float acc0 = 0.f, acc1 = 0.f, acc2 = 0.f, acc3 = 0.f;
    for (int p = beg; p < end; ++p) {
        int e = perm[p];
        e = min(max(e, 0), E - 1);
        float4 t = v[e];
        acc0 += t.x; acc1 += t.y; acc2 += t.z; acc3 += t.w;
    }
    float inv = 1.0f / fmaxf((float)(end - beg), 1.0f);
    float4 o;
    o.x = acc0 * inv; o.y = acc1 * inv; o.z = acc2 * inv; o.w = acc3 * inv;
    reinterpret_cast<float4*>(out)[i] = o;
}

// ---------------- Fallback (round-1 atomic path) ----------------
__global__ __launch_bounds__(256) void enc_edge_kernel(
    const float* __restrict__ x, const int* __restrict__ src, const int* __restrict__ dst,
    const float* __restrict__ ab,
    const float* __restrict__ W1, const float* __restrict__ b1,
    const float* __restrict__ W2, const float* __restrict__ b2,
    const float* __restrict__ W3, const float* __restrict__ b3,
    float* __restrict__ acc, float* __restrict__ cnt, int E)
{
    int e = blockIdx.x * blockDim.x + threadIdx.x;
    if (e >= E) return;
    int si = src[e];
    int di = dst[e];
    float4 xd = reinterpret_cast<const float4*>(x)[di];
    float4 xs = reinterpret_cast<const float4*>(x)[si];
    float a0 = ab[0], a1 = ab[1], a2 = ab[2], a3 = ab[3];
    float c0 = ab[4], c1 = ab[5], c2 = ab[6], c3 = ab[7];
    float in[2 * DD];
    in[0] = fmaf(xd.x, a0, c0); in[1] = fmaf(xd.y, a1, c1);
    in[2] = fmaf(xd.z, a2, c2); in[3] = fmaf(xd.w, a3, c3);
    in[4] = (xs.x - xd.x) * a0; in[5] = (xs.y - xd.y) * a1;
    in[6] = (xs.z - xd.z) * a2; in[7] = (xs.w - xd.w) * a3;
    float h[BIG];
    #pragma unroll
    for (int j = 0; j < BIG; ++j) {
        float t = b1[j];
        #pragma unroll
        for (int k = 0; k < 2 * DD; ++k) t = fmaf(in[k], W1[k * BIG + j], t);
        h[j] = fmaxf(t, 0.0f);
    }
    float g[BIG];
    #pragma unroll
    for (int j = 0; j < BIG; ++j) {
        float t = b2[j];
        #pragma unroll
        for (int k = 0; k < BIG; ++k) t = fmaf(h[k], W2[k * BIG + j], t);
        g[j] = fmaxf(t, 0.0f);
    }
    float u0 = b3[0], u1 = b3[1];
    #pragma unroll
    for (int k = 0; k < BIG; ++k) {
        u0 = fmaf(g[k], W3[k * HID + 0], u0);
        u1 = fmaf(g[k], W3[k * HID + 1], u1);
    }
    atomicAdd(&acc[di * HID + 0], fmaxf(u0, 0.0f));
    atomicAdd(&acc[di * HID + 1], fmaxf(u1, 0.0f));
    atomicAdd(&cnt[di], 1.0f);
}

__global__ void finalize_h1_kernel(float* __restrict__ acc, const float* __restrict__ cnt, int n)
{
    int i = blockIdx.x * blockDim.x + threadIdx.x;
    if (i >= n) return;
    float inv = 1.0f / fmaxf(cnt[i], 1.0f);
    acc[i * HID + 0] *= inv;
    acc[i * HID + 1] *= inv;
}

__global__ __launch_bounds__(256) void dec_edge_kernel(
    const float* __restrict__ h1, const int* __restrict__ src, const int* __restrict__ dst,
    const float* __restrict__ W1, const float* __restrict__ b1,
    const float* __restrict__ W2, const float* __restrict__ b2,
    const float* __restrict__ W3, const float* __restrict__ b3,
    float* __restrict__ out, int E)
{
    int e = blockIdx.x * blockDim.x + threadIdx.x;
    if (e >= E) return;
    int si = src[e];
    int di = dst[e];
    float2 hd = reinterpret_cast<const float2*>(h1)[di];
    float2 hs = reinterpret_cast<const float2*>(h1)[si];
    float in[2 * HID];
    in[0] = hd.x; in[1] = hd.y;
    in[2] = hs.x - hd.x; in[3] = hs.y - hd.y;
    float h[BIG];
    #pragma unroll
    for (int j = 0; j < BIG; ++j) {
        float t = b1[j];
        #pragma unroll
        for (int k = 0; k < 2 * HID; ++k) t = fmaf(in[k], W1[k * BIG + j], t);
        h[j] = fmaxf(t, 0.0f);
    }
    float g[BIG];
    #pragma unroll
    for (int j = 0; j < BIG; ++j) {
        float t = b2[j];
        #pragma unroll
        for (int k = 0; k < BIG; ++k) t = fmaf(h[k], W2[k * BIG + j], t);
        g[j] = fmaxf(t, 0.0f);
    }
    float u0 = b3[0], u1 = b3[1], u2 = b3[2], u3 = b3[3];
    #pragma unroll
    for (int k = 0; k < BIG; ++k) {
        u0 = fmaf(g[k], W3[k * DD + 0], u0);
        u1 = fmaf(g[k], W3[k * DD + 1], u1);
        u2 = fmaf(g[k], W3[k * DD + 2], u2);
        u3 = fmaf(g[k], W3[k * DD + 3], u3);
    }
    atomicAdd(&out[di * DD + 0], u0);
    atomicAdd(&out[di * DD + 1], u1);
    atomicAdd(&out[di * DD + 2], u2);
    atomicAdd(&out[di * DD + 3], u3);
}

__global__ void finalize_out_kernel(float* __restrict__ out, const float* __restrict__ cnt, int n)
{
    int i = blockIdx.x * blockDim.x + threadIdx.x;
    if (i >= n) return;
    float inv = 1.0f / fmaxf(cnt[i], 1.0f);
    float4 v = reinterpret_cast<float4*>(out)[i];
    v.x *= inv; v.y *= inv; v.z *= inv; v.w *= inv;
    reinterpret_cast<float4*>(out)[i] = v;
}

// ---------------- launch ----------------
extern "C" void kernel_launch(void* const* d_in, const int* in_sizes, int n_in,
                              void* d_out, int out_size, void* d_ws, size_t ws_size,
                              hipStream_t stream)
{
    const float* x     = (const float*)d_in[0];
    const int*   src   = (const int*)  d_in[1];
    const int*   dst   = (const int*)  d_in[2];
    const float* gamma = (const float*)d_in[3];
    const float* beta  = (const float*)d_in[4];
    const float* eW1 = (const float*)d_in[5];  const float* eb1 = (const float*)d_in[6];
    const float* eW2 = (const float*)d_in[7];  const float* eb2 = (const float*)d_in[8];
    const float* eW3 = (const float*)d_in[9];  const float* eb3 = (const float*)d_in[10];
    const float* dW1 = (const float*)d_in[11]; const float* db1 = (const float*)d_in[12];
    const float* dW2 = (const float*)d_in[13]; const float* db2 = (const float*)d_in[14];
    const float* dW3 = (const float*)d_in[15]; const float* db3 = (const float*)d_in[16];

    const int N = in_sizes[0] / DD;
    const int E = in_sizes[1];
    float* out = (float*)d_out;

    // workspace layout (CSR path). "big" region is a time-multiplexed union:
    // rank (E*2, dead after scatter) -> u (E*8, dead after enc_reduce) -> v (E*16).
    auto rnd16 = [](size_t b) { return (b + 15) & ~(size_t)15; };
    size_t need = 0;
    size_t o_sums  = need; need += rnd16(8 * 4);
    size_t o_ab    = need; need += rnd16(8 * 4);
    size_t o_bsum  = need; need += rnd16(256 * 4);
    size_t o_bbase = need; need += rnd16(256 * 4);
    size_t o_deg   = need; need += rnd16((size_t)N * 4);
    size_t o_off   = need; need += rnd16((size_t)(N + 1) * 4);
    size_t o_h1    = need; need += rnd16((size_t)2 * N * 4);
    size_t o_perm  = need; need += rnd16((size_t)E * 4);
    size_t o_big   = need; need += rnd16((size_t)E * 16);  // max(E*2, E*8, E*16)

    char* wsb = (char*)d_ws;

    if (ws_size >= need && N > 0 && E > 0) {
        float*          sums  = (float*)(wsb + o_sums);
        float*          ab    = (float*)(wsb + o_ab);
        int*            bsum  = (int*)  (wsb + o_bsum);
        int*            bbase = (int*)  (wsb + o_bbase);
        int*            deg   = (int*)  (wsb + o_deg);
        int*            off   = (int*)  (wsb + o_off);
        float*          h1    = (float*)(wsb + o_h1);
        int*            perm  = (int*)  (wsb + o_perm);
        unsigned short* rank  = (unsigned short*)(wsb + o_big);
        float2*         u     = (float2*)(wsb + o_big);
        float4*         v     = (float4*)(wsb + o_big);

        hipMemsetAsync(sums, 0, 8 * sizeof(float), stream);
        hipMemsetAsync(deg, 0, (size_t)N * sizeof(int), stream);

        bn_reduce_kernel<<<256, 256, 0, stream>>>(x, N, sums);
        bn_finalize_kernel<<<1, 64, 0, stream>>>(sums, gamma, beta, ab, 1.0f / (float)N);

        int eblocks = (E + 255) / 256;
        int nblocks = (N + 255) / 256;

        rank_hist_kernel<<<eblocks, 256, 0, stream>>>(dst, E, deg, rank);

        int nb = (N + SCAN_CHUNK - 1) / SCAN_CHUNK;  // 98 blocks for N=100000
        scan_block_sums_kernel<<<nb, 256, 0, stream>>>(deg, N, bsum);
        scan_base_kernel<<<1, 64, 0, stream>>>(bsum, nb, bbase);
        scan_write_kernel<<<nb, 256, 0, stream>>>(deg, N, bbase, off);

        scatter_perm_kernel<<<eblocks, 256, 0, stream>>>(dst, rank, off, perm, E);
        // rank dead from here; "big" region reused for u, then v.

        enc_mlp_kernel<<<eblocks, 256, 0, stream>>>(x, src, dst, ab,
                                                    eW1, eb1, eW2, eb2, eW3, eb3, u, E);
        enc_reduce_kernel<<<nblocks, 256, 0, stream>>>(u, perm, off, h1, N, E);
        // u dead from here; same region becomes v.

        dec_mlp_kernel<<<eblocks, 256, 0, stream>>>(h1, src, dst,
                                                    dW1, db1, dW2, db2, dW3, db3, v, E);
        dec_reduce_kernel<<<nblocks, 256, 0, stream>>>(v, perm, off, out, N, E);
    } else {
        // fallback: round-1 atomic path (needs only (16+3N) floats)
        float* ws   = (float*)d_ws;
        float* sums = ws;
        float* ab   = ws + 8;
        float* cnt  = ws + 16;
        float* acc1 = ws + 16 + N;

        hipMemsetAsync(sums, 0, 16 * sizeof(float), stream);
        hipMemsetAsync(cnt, 0, (size_t)(3 * N) * sizeof(float), stream);
        hipMemsetAsync(out, 0, (size_t)out_size * sizeof(float), stream);

        bn_reduce_kernel<<<256, 256, 0, stream>>>(x, N, sums);
        bn_finalize_kernel<<<1, 64, 0, stream>>>(sums, gamma, beta, ab, 1.0f / (float)N);

        int eblocks = (E + 255) / 256;
        enc_edge_kernel<<<eblocks, 256, 0, stream>>>(x, src, dst, ab,
                                                     eW1, eb1, eW2, eb2, eW3, eb3,
                                                     acc1, cnt, E);
        finalize_h1_kernel<<<(N + 255) / 256, 256, 0, stream>>>(acc1, cnt, N);
        dec_edge_kernel<<<eblocks, 256, 0, stream>>>(acc1, src, dst,
                                                     dW1, db1, dW2, db2, dW3, db3,
                                                     out, E);
        finalize_out_kernel<<<(N + 255) / 256, 256, 0, stream>>>(out, cnt, N);
    }
}

// Round 5
// 451.159 us; speedup vs baseline: 8.9373x; 1.2659x over previous
//
#include <hip/hip_runtime.h>
#include <hip/hip_bf16.h>
#include <math.h>

// EdgeNetEMD: BatchNorm(4) -> EdgeConv(8->32->32->2, relu_last) -> EdgeConv(4->32->32->4)
// N=100000 nodes, E=3200000 edges, fp32 in/out.
// Round 5: per-edge MLPs moved to MFMA (bf16 operands, fp32 accum).
// Wave processes 16 edges/batch: H^T = W^T * In^T per layer, LDS bounce between
// layers. CSR build + segment reduces unchanged from round 4.

constexpr int DD  = 4;
constexpr int BIG = 32;
constexpr int HID = 2;

typedef __attribute__((ext_vector_type(8))) short bf16x8;
typedef __attribute__((ext_vector_type(4))) float f32x4;
typedef unsigned int u32;

union frag_u { bf16x8 v; u32 w[4]; };

__device__ inline unsigned short bfbits(float f) {
    __hip_bfloat16 h = __float2bfloat16(f);
    unsigned short s; __builtin_memcpy(&s, &h, 2); return s;
}
__device__ inline u32 pkbf(float lo, float hi) {
    return (u32)bfbits(lo) | ((u32)bfbits(hi) << 16);
}

// ---------------- BatchNorm statistics ----------------
__global__ void bn_reduce_kernel(const float* __restrict__ x, int n,
                                 float* __restrict__ sums)
{
    float s0=0.f,s1=0.f,s2=0.f,s3=0.f,q0=0.f,q1=0.f,q2=0.f,q3=0.f;
    int stride = gridDim.x * blockDim.x;
    for (int i = blockIdx.x * blockDim.x + threadIdx.x; i < n; i += stride) {
        float4 v = reinterpret_cast<const float4*>(x)[i];
        s0 += v.x; s1 += v.y; s2 += v.z; s3 += v.w;
        q0 = fmaf(v.x, v.x, q0); q1 = fmaf(v.y, v.y, q1);
        q2 = fmaf(v.z, v.z, q2); q3 = fmaf(v.w, v.w, q3);
    }
    #pragma unroll
    for (int off = 32; off >= 1; off >>= 1) {
        s0 += __shfl_down(s0, off); s1 += __shfl_down(s1, off);
        s2 += __shfl_down(s2, off); s3 += __shfl_down(s3, off);
        q0 += __shfl_down(q0, off); q1 += __shfl_down(q1, off);
        q2 += __shfl_down(q2, off); q3 += __shfl_down(q3, off);
    }
    __shared__ float red[4][8];
    int wave = threadIdx.x >> 6;
    int lane = threadIdx.x & 63;
    if (lane == 0) {
        red[wave][0]=s0; red[wave][1]=s1; red[wave][2]=s2; red[wave][3]=s3;
        red[wave][4]=q0; red[wave][5]=q1; red[wave][6]=q2; red[wave][7]=q3;
    }
    __syncthreads();
    if (threadIdx.x < 8) {
        int nw = blockDim.x >> 6;
        float t = 0.f;
        for (int w = 0; w < nw; ++w) t += red[w][threadIdx.x];
        atomicAdd(&sums[threadIdx.x], t);
    }
}

__global__ void bn_finalize_kernel(const float* __restrict__ sums,
                                   const float* __restrict__ gamma,
                                   const float* __restrict__ beta,
                                   float* __restrict__ ab, float invN)
{
    int f = threadIdx.x;
    if (f < DD) {
        float mean = sums[f] * invN;
        float var  = sums[DD + f] * invN - mean * mean;
        float a = gamma[f] / sqrtf(var + 1e-5f);
        ab[f]      = a;
        ab[DD + f] = beta[f] - mean * a;
    }
}

// ---------------- CSR construction ----------------
__global__ __launch_bounds__(256) void rank_hist_kernel(const int* __restrict__ dst, int E,
                                                        int* __restrict__ deg,
                                                        unsigned short* __restrict__ rank)
{
    int e = blockIdx.x * 256 + threadIdx.x;
    if (e >= E) return;
    int d = dst[e];
    int old = atomicAdd(&deg[d], 1);
    rank[e] = (unsigned short)old;
}

constexpr int SCAN_CHUNK = 1024;

__global__ __launch_bounds__(256) void scan_block_sums_kernel(const int* __restrict__ deg, int n,
                                                              int* __restrict__ bsum)
{
    int b = blockIdx.x;
    int base = b * SCAN_CHUNK + threadIdx.x * 4;
    int s = 0;
    #pragma unroll
    for (int k = 0; k < 4; ++k) { int i = base + k; if (i < n) s += deg[i]; }
    #pragma unroll
    for (int o = 32; o >= 1; o >>= 1) s += __shfl_down(s, o);
    __shared__ int red[4];
    int wave = threadIdx.x >> 6, lane = threadIdx.x & 63;
    if (lane == 0) red[wave] = s;
    __syncthreads();
    if (threadIdx.x == 0) bsum[b] = red[0] + red[1] + red[2] + red[3];
}

// bsum and bbase MUST be separate buffers (round-2 aliasing fault).
__global__ void scan_base_kernel(const int* bsum, int nb, int* bbase)
{
    if (threadIdx.x == 0) {
        int running = 0;
        for (int b = 0; b < nb; ++b) {
            int v = bsum[b];
            bbase[b] = running;
            running += v;
        }
    }
}

__global__ __launch_bounds__(256) void scan_write_kernel(const int* __restrict__ deg, int n,
                                                         const int* __restrict__ bbase,
                                                         int* __restrict__ off)
{
    int b = blockIdx.x, tid = threadIdx.x;
    int base = b * SCAN_CHUNK + tid * 4;
    int v[4]; int s = 0;
    #pragma unroll
    for (int k = 0; k < 4; ++k) { int i = base + k; v[k] = (i < n) ? deg[i] : 0; s += v[k]; }
    int lane = tid & 63, wave = tid >> 6;
    int inc = s;
    #pragma unroll
    for (int o = 1; o < 64; o <<= 1) { int t = __shfl_up(inc, o); if (lane >= o) inc += t; }
    __shared__ int wsum[4];
    if (lane == 63) wsum[wave] = inc;
    __syncthreads();
    int wbase = 0;
    for (int w = 0; w < wave; ++w) wbase += wsum[w];
    int cur = bbase[b] + wbase + inc - s;
    #pragma unroll
    for (int k = 0; k < 4; ++k) {
        int i = base + k;
        if (i < n) {
            off[i] = cur;
            cur += v[k];
            if (i == n - 1) off[n] = cur;
        }
    }
}

__global__ __launch_bounds__(256) void scatter_perm_kernel(const int* __restrict__ dst,
                                                           const unsigned short* __restrict__ rank,
                                                           const int* __restrict__ off,
                                                           int* __restrict__ perm, int E)
{
    int e = blockIdx.x * 256 + threadIdx.x;
    if (e >= E) return;
    int d = dst[e];
    int idx = off[d] + (int)rank[e];
    idx = min(max(idx, 0), E - 1);
    perm[idx] = e;
}

// ---------------- Encoder per-edge MLP via MFMA ----------------
// Per wave, per batch of 16 edges: In^T [K x 16edges], H^T = W^T * In^T.
// Logical k-mapping for A/B fragments: k = 8*(lane>>4) + i (self-consistent for
// A and B => contraction is correct for any positionally-symmetric HW layout).
// C/D layout (HW-verified m89): col = lane&15 (edge), row = 4*(lane>>4)+reg (feat).
__global__ __launch_bounds__(256) void enc_mfma_kernel(
    const float* __restrict__ x, const int* __restrict__ src, const int* __restrict__ dst,
    const float* __restrict__ ab,
    const float* __restrict__ W1, const float* __restrict__ b1,
    const float* __restrict__ W2, const float* __restrict__ b2,
    const float* __restrict__ W3, const float* __restrict__ b3,
    float2* __restrict__ u, int N, int E, int nbatch, int nwaves)
{
    __shared__ __align__(16) char lds_all[4][16 * 80];
    const int tid  = threadIdx.x;
    const int wid  = tid >> 6;
    const int lane = tid & 63;
    const int c    = lane & 15;
    const int g    = lane >> 4;
    char* lds = lds_all[wid];

    // ---- weight fragments (once per kernel) ----
    // L1: A[of][k] = k<8 ? W1[k*32+of] : 0 ; nonzero only for g==0 (k=i).
    frag_u A1[2];
    #pragma unroll
    for (int t = 0; t < 2; ++t) {
        A1[t].w[0] = A1[t].w[1] = A1[t].w[2] = A1[t].w[3] = 0;
        if (g == 0) {
            int of = 16 * t + c;
            #pragma unroll
            for (int j = 0; j < 4; ++j)
                A1[t].w[j] = pkbf(W1[(2*j+0)*BIG + of], W1[(2*j+1)*BIG + of]);
        }
    }
    // L2: A[of][k] = W2[k*32+of], k = 8g+i (full K=32).
    frag_u A2[2];
    #pragma unroll
    for (int t = 0; t < 2; ++t) {
        int of = 16 * t + c;
        #pragma unroll
        for (int j = 0; j < 4; ++j)
            A2[t].w[j] = pkbf(W2[(8*g + 2*j + 0)*BIG + of], W2[(8*g + 2*j + 1)*BIG + of]);
    }
    // L3: A[of][k] = of<2 ? W3[k*2+of] : 0
    frag_u A3;
    A3.w[0] = A3.w[1] = A3.w[2] = A3.w[3] = 0;
    if (c < HID) {
        #pragma unroll
        for (int j = 0; j < 4; ++j)
            A3.w[j] = pkbf(W3[(8*g + 2*j + 0)*HID + c], W3[(8*g + 2*j + 1)*HID + c]);
    }
    // biases per (tile, row): row feat = 16t + 4g + r
    float4 b1v0 = *reinterpret_cast<const float4*>(b1 + 4*g);
    float4 b1v1 = *reinterpret_cast<const float4*>(b1 + 16 + 4*g);
    float4 b2v0 = *reinterpret_cast<const float4*>(b2 + 4*g);
    float4 b2v1 = *reinterpret_cast<const float4*>(b2 + 16 + 4*g);
    float b30 = b3[0], b31 = b3[1];
    float a0 = ab[0], a1 = ab[1], a2 = ab[2], a3 = ab[3];
    float c0 = ab[4], c1 = ab[5], c2 = ab[6], c3 = ab[7];

    const f32x4 zero4 = {0.f, 0.f, 0.f, 0.f};

    for (int batch = blockIdx.x * 4 + wid; batch < nbatch; batch += nwaves) {
        int ebase = batch * 16;
        int e = min(ebase + c, E - 1);

        // lanes 0-15: gather x[dst[e]]; lanes 16-31: gather x[src[e]]
        float4 xv = make_float4(0.f, 0.f, 0.f, 0.f);
        if (lane < 32) {
            const int* ip = (lane < 16) ? dst : src;
            int idx = ip[e];
            idx = min(max(idx, 0), N - 1);
            xv = reinterpret_cast<const float4*>(x)[idx];
        }
        float xd0 = __shfl(xv.x, c),      xd1 = __shfl(xv.y, c);
        float xd2 = __shfl(xv.z, c),      xd3 = __shfl(xv.w, c);
        float xs0 = __shfl(xv.x, 16 + c), xs1 = __shfl(xv.y, 16 + c);
        float xs2 = __shfl(xv.z, 16 + c), xs3 = __shfl(xv.w, 16 + c);

        float n0 = fmaf(xd0, a0, c0), n1 = fmaf(xd1, a1, c1);
        float n2 = fmaf(xd2, a2, c2), n3 = fmaf(xd3, a3, c3);
        float d0 = (xs0 - xd0) * a0,  d1 = (xs1 - xd1) * a1;
        float d2 = (xs2 - xd2) * a2,  d3 = (xs3 - xd3) * a3;

        // B1: In^T, k = 8g+i ; k<8 real -> only g==0.
        frag_u B1;
        if (g == 0) {
            B1.w[0] = pkbf(n0, n1); B1.w[1] = pkbf(n2, n3);
            B1.w[2] = pkbf(d0, d1); B1.w[3] = pkbf(d2, d3);
        } else {
            B1.w[0] = B1.w[1] = B1.w[2] = B1.w[3] = 0;
        }

        // ---- layer 1 ----
        f32x4 D0 = __builtin_amdgcn_mfma_f32_16x16x32_bf16(A1[0].v, B1.v, zero4, 0, 0, 0);
        f32x4 D1 = __builtin_amdgcn_mfma_f32_16x16x32_bf16(A1[1].v, B1.v, zero4, 0, 0, 0);
        // relu(D + b1) -> LDS [edge c][feat f] bf16 at byte 2f (stride 80)
        {
            float h0 = fmaxf(D0[0] + b1v0.x, 0.f), h1 = fmaxf(D0[1] + b1v0.y, 0.f);
            float h2 = fmaxf(D0[2] + b1v0.z, 0.f), h3 = fmaxf(D0[3] + b1v0.w, 0.f);
            *reinterpret_cast<uint2*>(lds + c*80 + 8*g) = make_uint2(pkbf(h0, h1), pkbf(h2, h3));
            float k0 = fmaxf(D1[0] + b1v1.x, 0.f), k1 = fmaxf(D1[1] + b1v1.y, 0.f);
            float k2 = fmaxf(D1[2] + b1v1.z, 0.f), k3 = fmaxf(D1[3] + b1v1.w, 0.f);
            *reinterpret_cast<uint2*>(lds + c*80 + 32 + 8*g) = make_uint2(pkbf(k0, k1), pkbf(k2, k3));
        }
        // B2: feats 8g..8g+7 of edge c
        frag_u B2;
        *reinterpret_cast<uint4*>(&B2.w[0]) = *reinterpret_cast<const uint4*>(lds + c*80 + 16*g);

        // ---- layer 2 ----
        f32x4 E0 = __builtin_amdgcn_mfma_f32_16x16x32_bf16(A2[0].v, B2.v, zero4, 0, 0, 0);
        f32x4 E1 = __builtin_amdgcn_mfma_f32_16x16x32_bf16(A2[1].v, B2.v, zero4, 0, 0, 0);
        {
            float h0 = fmaxf(E0[0] + b2v0.x, 0.f), h1 = fmaxf(E0[1] + b2v0.y, 0.f);
            float h2 = fmaxf(E0[2] + b2v0.z, 0.f), h3 = fmaxf(E0[3] + b2v0.w, 0.f);
            *reinterpret_cast<uint2*>(lds + c*80 + 8*g) = make_uint2(pkbf(h0, h1), pkbf(h2, h3));
            float k0 = fmaxf(E1[0] + b2v1.x, 0.f), k1 = fmaxf(E1[1] + b2v1.y, 0.f);
            float k2 = fmaxf(E1[2] + b2v1.z, 0.f), k3 = fmaxf(E1[3] + b2v1.w, 0.f);
            *reinterpret_cast<uint2*>(lds + c*80 + 32 + 8*g) = make_uint2(pkbf(k0, k1), pkbf(k2, k3));
        }
        frag_u B3;
        *reinterpret_cast<uint4*>(&B3.w[0]) = *reinterpret_cast<const uint4*>(lds + c*80 + 16*g);

        // ---- layer 3 ----
        f32x4 F = __builtin_amdgcn_mfma_f32_16x16x32_bf16(A3.v, B3.v, zero4, 0, 0, 0);
        // rows 0,1 (g==0, regs 0,1) = u0,u1 for edge c
        if (lane < 16 && (ebase + c) < E) {
            float2 o;
            o.x = fmaxf(F[0] + b30, 0.f);
            o.y = fmaxf(F[1] + b31, 0.f);
            u[ebase + c] = o;
        }
    }
}

// ---------------- Decoder per-edge MLP via MFMA ----------------
__global__ __launch_bounds__(256) void dec_mfma_kernel(
    const float* __restrict__ h1n, const int* __restrict__ src, const int* __restrict__ dst,
    const float* __restrict__ W1, const float* __restrict__ b1,
    const float* __restrict__ W2, const float* __restrict__ b2,
    const float* __restrict__ W3, const float* __restrict__ b3,
    float4* __restrict__ v, int N, int E, int nbatch, int nwaves)
{
    __shared__ __align__(16) char lds_all[4][16 * 80];
    const int tid  = threadIdx.x;
    const int wid  = tid >> 6;
    const int lane = tid & 63;
    const int c    = lane & 15;
    const int g    = lane >> 4;
    char* lds = lds_all[wid];

    // L1: in-dim 4: A[of][k] = k<4 ? W1[k*32+of] : 0 (g==0, i<4)
    frag_u A1[2];
    #pragma unroll
    for (int t = 0; t < 2; ++t) {
        A1[t].w[0] = A1[t].w[1] = A1[t].w[2] = A1[t].w[3] = 0;
        if (g == 0) {
            int of = 16 * t + c;
            A1[t].w[0] = pkbf(W1[0*BIG + of], W1[1*BIG + of]);
            A1[t].w[1] = pkbf(W1[2*BIG + of], W1[3*BIG + of]);
        }
    }
    frag_u A2[2];
    #pragma unroll
    for (int t = 0; t < 2; ++t) {
        int of = 16 * t + c;
        #pragma unroll
        for (int j = 0; j < 4; ++j)
            A2[t].w[j] = pkbf(W2[(8*g + 2*j + 0)*BIG + of], W2[(8*g + 2*j + 1)*BIG + of]);
    }
    frag_u A3;
    A3.w[0] = A3.w[1] = A3.w[2] = A3.w[3] = 0;
    if (c < DD) {
        #pragma unroll
        for (int j = 0; j < 4; ++j)
            A3.w[j] = pkbf(W3[(8*g + 2*j + 0)*DD + c], W3[(8*g + 2*j + 1)*DD + c]);
    }
    float4 b1v0 = *reinterpret_cast<const float4*>(b1 + 4*g);
    float4 b1v1 = *reinterpret_cast<const float4*>(b1 + 16 + 4*g);
    float4 b2v0 = *reinterpret_cast<const float4*>(b2 + 4*g);
    float4 b2v1 = *reinterpret_cast<const float4*>(b2 + 16 + 4*g);
    float b30 = b3[0], b31 = b3[1], b32 = b3[2], b33 = b3[3];

    const f32x4 zero4 = {0.f, 0.f, 0.f, 0.f};

    for (int batch = blockIdx.x * 4 + wid; batch < nbatch; batch += nwaves) {
        int ebase = batch * 16;
        int e = min(ebase + c, E - 1);

        float2 hv = make_float2(0.f, 0.f);
        if (lane < 32) {
            const int* ip = (lane < 16) ? dst : src;
            int idx = ip[e];
            idx = min(max(idx, 0), N - 1);
            hv = reinterpret_cast<const float2*>(h1n)[idx];
        }
        float hd0 = __shfl(hv.x, c),      hd1 = __shfl(hv.y, c);
        float hs0 = __shfl(hv.x, 16 + c), hs1 = __shfl(hv.y, 16 + c);
        float i0 = hd0, i1 = hd1, i2 = hs0 - hd0, i3 = hs1 - hd1;

        frag_u B1;
        if (g == 0) {
            B1.w[0] = pkbf(i0, i1); B1.w[1] = pkbf(i2, i3);
            B1.w[2] = 0; B1.w[3] = 0;
        } else {
            B1.w[0] = B1.w[1] = B1.w[2] = B1.w[3] = 0;
        }

        f32x4 D0 = __builtin_amdgcn_mfma_f32_16x16x32_bf16(A1[0].v, B1.v, zero4, 0, 0, 0);
        f32x4 D1 = __builtin_amdgcn_mfma_f32_16x16x32_bf16(A1[1].v, B1.v, zero4, 0, 0, 0);
        {
            float h0 = fmaxf(D0[0] + b1v0.x, 0.f), h1 = fmaxf(D0[1] + b1v0.y, 0.f);
            float h2 = fmaxf(D0[2] + b1v0.z, 0.f), h3 = fmaxf(D0[3] + b1v0.w, 0.f);
            *reinterpret_cast<uint2*>(lds + c*80 + 8*g) = make_uint2(pkbf(h0, h1), pkbf(h2, h3));
            float k0 = fmaxf(D1[0] + b1v1.x, 0.f), k1 = fmaxf(D1[1] + b1v1.y, 0.f);
            float k2 = fmaxf(D1[2] + b1v1.z, 0.f), k3 = fmaxf(D1[3] + b1v1.w, 0.f);
            *reinterpret_cast<uint2*>(lds + c*80 + 32 + 8*g) = make_uint2(pkbf(k0, k1), pkbf(k2, k3));
        }
        frag_u B2;
        *reinterpret_cast<uint4*>(&B2.w[0]) = *reinterpret_cast<const uint4*>(lds + c*80 + 16*g);

        f32x4 E0 = __builtin_amdgcn_mfma_f32_16x16x32_bf16(A2[0].v, B2.v, zero4, 0, 0, 0);
        f32x4 E1 = __builtin_amdgcn_mfma_f32_16x16x32_bf16(A2[1].v, B2.v, zero4, 0, 0, 0);
        {
            float h0 = fmaxf(E0[0] + b2v0.x, 0.f), h1 = fmaxf(E0[1] + b2v0.y, 0.f);
            float h2 = fmaxf(E0[2] + b2v0.z, 0.f), h3 = fmaxf(E0[3] + b2v0.w, 0.f);
            *reinterpret_cast<uint2*>(lds + c*80 + 8*g) = make_uint2(pkbf(h0, h1), pkbf(h2, h3));
            float k0 = fmaxf(E1[0] + b2v1.x, 0.f), k1 = fmaxf(E1[1] + b2v1.y, 0.f);
            float k2 = fmaxf(E1[2] + b2v1.z, 0.f), k3 = fmaxf(E1[3] + b2v1.w, 0.f);
            *reinterpret_cast<uint2*>(lds + c*80 + 32 + 8*g) = make_uint2(pkbf(k0, k1), pkbf(k2, k3));
        }
        frag_u B3;
        *reinterpret_cast<uint4*>(&B3.w[0]) = *reinterpret_cast<const uint4*>(lds + c*80 + 16*g);

        f32x4 F = __builtin_amdgcn_mfma_f32_16x16x32_bf16(A3.v, B3.v, zero4, 0, 0, 0);
        if (lane < 16 && (ebase + c) < E) {
            float4 o;
            o.x = F[0] + b30; o.y = F[1] + b31; o.z = F[2] + b32; o.w = F[3] + b33;
            v[ebase + c] = o;
        }
    }
}

// ---------------- segment reduces ----------------
__global__ __launch_bounds__(256) void enc_reduce_kernel(
    const float2* __restrict__ u, const int* __restrict__ perm, const int* __restrict__ off,
    float* __restrict__ h1, int N, int E)
{
    int i = blockIdx.x * 256 + threadIdx.x;
    if (i >= N) return;
    int beg = off[i], end = off[i + 1];
    float acc0 = 0.f, acc1 = 0.f;
    for (int p = beg; p < end; ++p) {
        int e = perm[p];
        e = min(max(e, 0), E - 1);
        float2 t = u[e];
        acc0 += t.x; acc1 += t.y;
    }
    float inv = 1.0f / fmaxf((float)(end - beg), 1.0f);
    float2 o; o.x = acc0 * inv; o.y = acc1 * inv;
    reinterpret_cast<float2*>(h1)[i] = o;
}

__global__ __launch_bounds__(256) void dec_reduce_kernel(
    const float4* __restrict__ v, const int* __restrict__ perm, const int* __restrict__ off,
    float* __restrict__ out, int N, int E)
{
    int i = blockIdx.x * 256 + threadIdx.x;
    if (i >= N) return;
    int beg = off[i], end = off[i + 1];
    float acc0 = 0.f, acc1 = 0.f, acc2 = 0.f, acc3 = 0.f;
    for (int p = beg; p < end; ++p) {
        int e = perm[p];
        e = min(max(e, 0), E - 1);
        float4 t = v[e];
        acc0 += t.x; acc1 += t.y; acc2 += t.z; acc3 += t.w;
    }
    float inv = 1.0f / fmaxf((float)(end - beg), 1.0f);
    float4 o;
    o.x = acc0 * inv; o.y = acc1 * inv; o.z = acc2 * inv; o.w = acc3 * inv;
    reinterpret_cast<float4*>(out)[i] = o;
}

// ---------------- Fallback (round-1 atomic path) ----------------
__global__ __launch_bounds__(256) void enc_edge_kernel(
    const float* __restrict__ x, const int* __restrict__ src, const int* __restrict__ dst,
    const float* __restrict__ ab,
    const float* __restrict__ W1, const float* __restrict__ b1,
    const float* __restrict__ W2, const float* __restrict__ b2,
    const float* __restrict__ W3, const float* __restrict__ b3,
    float* __restrict__ acc, float* __restrict__ cnt, int E)
{
    int e = blockIdx.x * blockDim.x + threadIdx.x;
    if (e >= E) return;
    int si = src[e];
    int di = dst[e];
    float4 xd = reinterpret_cast<const float4*>(x)[di];
    float4 xs = reinterpret_cast<const float4*>(x)[si];
    float a0 = ab[0], a1 = ab[1], a2 = ab[2], a3 = ab[3];
    float c0 = ab[4], c1 = ab[5], c2 = ab[6], c3 = ab[7];
    float in[2 * DD];
    in[0] = fmaf(xd.x, a0, c0); in[1] = fmaf(xd.y, a1, c1);
    in[2] = fmaf(xd.z, a2, c2); in[3] = fmaf(xd.w, a3, c3);
    in[4] = (xs.x - xd.x) * a0; in[5] = (xs.y - xd.y) * a1;
    in[6] = (xs.z - xd.z) * a2; in[7] = (xs.w - xd.w) * a3;
    float h[BIG];
    #pragma unroll
    for (int j = 0; j < BIG; ++j) {
        float t = b1[j];
        #pragma unroll
        for (int k = 0; k < 2 * DD; ++k) t = fmaf(in[k], W1[k * BIG + j], t);
        h[j] = fmaxf(t, 0.0f);
    }
    float g[BIG];
    #pragma unroll
    for (int j = 0; j < BIG; ++j) {
        float t = b2[j];
        #pragma unroll
        for (int k = 0; k < BIG; ++k) t = fmaf(h[k], W2[k * BIG + j], t);
        g[j] = fmaxf(t, 0.0f);
    }
    float u0 = b3[0], u1 = b3[1];
    #pragma unroll
    for (int k = 0; k < BIG; ++k) {
        u0 = fmaf(g[k], W3[k * HID + 0], u0);
        u1 = fmaf(g[k], W3[k * HID + 1], u1);
    }
    atomicAdd(&acc[di * HID + 0], fmaxf(u0, 0.0f));
    atomicAdd(&acc[di * HID + 1], fmaxf(u1, 0.0f));
    atomicAdd(&cnt[di], 1.0f);
}

__global__ void finalize_h1_kernel(float* __restrict__ acc, const float* __restrict__ cnt, int n)
{
    int i = blockIdx.x * blockDim.x + threadIdx.x;
    if (i >= n) return;
    float inv = 1.0f / fmaxf(cnt[i], 1.0f);
    acc[i * HID + 0] *= inv;
    acc[i * HID + 1] *= inv;
}

__global__ __launch_bounds__(256) void dec_edge_kernel(
    const float* __restrict__ h1, const int* __restrict__ src, const int* __restrict__ dst,
    const float* __restrict__ W1, const float* __restrict__ b1,
    const float* __restrict__ W2, const float* __restrict__ b2,
    const float* __restrict__ W3, const float* __restrict__ b3,
    float* __restrict__ out, int E)
{
    int e = blockIdx.x * blockDim.x + threadIdx.x;
    if (e >= E) return;
    int si = src[e];
    int di = dst[e];
    float2 hd = reinterpret_cast<const float2*>(h1)[di];
    float2 hs = reinterpret_cast<const float2*>(h1)[si];
    float in[2 * HID];
    in[0] = hd.x; in[1] = hd.y;
    in[2] = hs.x - hd.x; in[3] = hs.y - hd.y;
    float h[BIG];
    #pragma unroll
    for (int j = 0; j < BIG; ++j) {
        float t = b1[j];
        #pragma unroll
        for (int k = 0; k < 2 * HID; ++k) t = fmaf(in[k], W1[k * BIG + j], t);
        h[j] = fmaxf(t, 0.0f);
    }
    float g[BIG];
    #pragma unroll
    for (int j = 0; j < BIG; ++j) {
        float t = b2[j];
        #pragma unroll
        for (int k = 0; k < BIG; ++k) t = fmaf(h[k], W2[k * BIG + j], t);
        g[j] = fmaxf(t, 0.0f);
    }
    float u0 = b3[0], u1 = b3[1], u2 = b3[2], u3 = b3[3];
    #pragma unroll
    for (int k = 0; k < BIG; ++k) {
        u0 = fmaf(g[k], W3[k * DD + 0], u0);
        u1 = fmaf(g[k], W3[k * DD + 1], u1);
        u2 = fmaf(g[k], W3[k * DD + 2], u2);
        u3 = fmaf(g[k], W3[k * DD + 3], u3);
    }
    atomicAdd(&out[di * DD + 0], u0);
    atomicAdd(&out[di * DD + 1], u1);
    atomicAdd(&out[di * DD + 2], u2);
    atomicAdd(&out[di * DD + 3], u3);
}

__global__ void finalize_out_kernel(float* __restrict__ out, const float* __restrict__ cnt, int n)
{
    int i = blockIdx.x * blockDim.x + threadIdx.x;
    if (i >= n) return;
    float inv = 1.0f / fmaxf(cnt[i], 1.0f);
    float4 v = reinterpret_cast<float4*>(out)[i];
    v.x *= inv; v.y *= inv; v.z *= inv; v.w *= inv;
    reinterpret_cast<float4*>(out)[i] = v;
}

// ---------------- launch ----------------
extern "C" void kernel_launch(void* const* d_in, const int* in_sizes, int n_in,
                              void* d_out, int out_size, void* d_ws, size_t ws_size,
                              hipStream_t stream)
{
    const float* x     = (const float*)d_in[0];
    const int*   src   = (const int*)  d_in[1];
    const int*   dst   = (const int*)  d_in[2];
    const float* gamma = (const float*)d_in[3];
    const float* beta  = (const float*)d_in[4];
    const float* eW1 = (const float*)d_in[5];  const float* eb1 = (const float*)d_in[6];
    const float* eW2 = (const float*)d_in[7];  const float* eb2 = (const float*)d_in[8];
    const float* eW3 = (const float*)d_in[9];  const float* eb3 = (const float*)d_in[10];
    const float* dW1 = (const float*)d_in[11]; const float* db1 = (const float*)d_in[12];
    const float* dW2 = (const float*)d_in[13]; const float* db2 = (const float*)d_in[14];
    const float* dW3 = (const float*)d_in[15]; const float* db3 = (const float*)d_in[16];

    const int N = in_sizes[0] / DD;
    const int E = in_sizes[1];
    float* out = (float*)d_out;

    auto rnd16 = [](size_t b) { return (b + 15) & ~(size_t)15; };
    size_t need = 0;
    size_t o_sums  = need; need += rnd16(8 * 4);
    size_t o_ab    = need; need += rnd16(8 * 4);
    size_t o_bsum  = need; need += rnd16(256 * 4);
    size_t o_bbase = need; need += rnd16(256 * 4);
    size_t o_deg   = need; need += rnd16((size_t)N * 4);
    size_t o_off   = need; need += rnd16((size_t)(N + 1) * 4);
    size_t o_h1    = need; need += rnd16((size_t)2 * N * 4);
    size_t o_perm  = need; need += rnd16((size_t)E * 4);
    size_t o_big   = need; need += rnd16((size_t)E * 16);  // union: rank(E*2) -> u(E*8) -> v(E*16)

    char* wsb = (char*)d_ws;

    if (ws_size >= need && N > 0 && E > 0) {
        float*          sums  = (float*)(wsb + o_sums);
        float*          ab    = (float*)(wsb + o_ab);
        int*            bsum  = (int*)  (wsb + o_bsum);
        int*            bbase = (int*)  (wsb + o_bbase);
        int*            deg   = (int*)  (wsb + o_deg);
        int*            off   = (int*)  (wsb + o_off);
        float*          h1    = (float*)(wsb + o_h1);
        int*            perm  = (int*)  (wsb + o_perm);
        unsigned short* rank  = (unsigned short*)(wsb + o_big);
        float2*         u     = (float2*)(wsb + o_big);
        float4*         v     = (float4*)(wsb + o_big);

        hipMemsetAsync(sums, 0, 8 * sizeof(float), stream);
        hipMemsetAsync(deg, 0, (size_t)N * sizeof(int), stream);

        bn_reduce_kernel<<<256, 256, 0, stream>>>(x, N, sums);
        bn_finalize_kernel<<<1, 64, 0, stream>>>(sums, gamma, beta, ab, 1.0f / (float)N);

        int eblocks = (E + 255) / 256;
        int nblocks = (N + 255) / 256;

        rank_hist_kernel<<<eblocks, 256, 0, stream>>>(dst, E, deg, rank);

        int nb = (N + SCAN_CHUNK - 1) / SCAN_CHUNK;
        scan_block_sums_kernel<<<nb, 256, 0, stream>>>(deg, N, bsum);
        scan_base_kernel<<<1, 64, 0, stream>>>(bsum, nb, bbase);
        scan_write_kernel<<<nb, 256, 0, stream>>>(deg, N, bbase, off);

        scatter_perm_kernel<<<eblocks, 256, 0, stream>>>(dst, rank, off, perm, E);
        // rank dead; big region becomes u, then v.

        int nbatch = (E + 15) / 16;
        int mblocks = 1024;
        int nwaves = mblocks * 4;
        enc_mfma_kernel<<<mblocks, 256, 0, stream>>>(x, src, dst, ab,
                                                     eW1, eb1, eW2, eb2, eW3, eb3,
                                                     u, N, E, nbatch, nwaves);
        enc_reduce_kernel<<<nblocks, 256, 0, stream>>>(u, perm, off, h1, N, E);

        dec_mfma_kernel<<<mblocks, 256, 0, stream>>>(h1, src, dst,
                                                     dW1, db1, dW2, db2, dW3, db3,
                                                     v, N, E, nbatch, nwaves);
        dec_reduce_kernel<<<nblocks, 256, 0, stream>>>(v, perm, off, out, N, E);
    } else {
        float* ws   = (float*)d_ws;
        float* sums = ws;
        float* ab   = ws + 8;
        float* cnt  = ws + 16;
        float* acc1 = ws + 16 + N;

        hipMemsetAsync(sums, 0, 16 * sizeof(float), stream);
        hipMemsetAsync(cnt, 0, (size_t)(3 * N) * sizeof(float), stream);
        hipMemsetAsync(out, 0, (size_t)out_size * sizeof(float), stream);

        bn_reduce_kernel<<<256, 256, 0, stream>>>(x, N, sums);
        bn_finalize_kernel<<<1, 64, 0, stream>>>(sums, gamma, beta, ab, 1.0f / (float)N);

        int eblocks = (E + 255) / 256;
        enc_edge_kernel<<<eblocks, 256, 0, stream>>>(x, src, dst, ab,
                                                     eW1, eb1, eW2, eb2, eW3, eb3,
                                                     acc1, cnt, E);
        finalize_h1_kernel<<<(N + 255) / 256, 256, 0, stream>>>(acc1, cnt, N);
        dec_edge_kernel<<<eblocks, 256, 0, stream>>>(acc1, src, dst,
                                                     dW1, db1, dW2, db2, dW3, db3,
                                                     out, E);
        finalize_out_kernel<<<(N + 255) / 256, 256, 0, stream>>>(out, cnt, N);
    }
}

// Round 6
// 368.481 us; speedup vs baseline: 10.9426x; 1.2244x over previous
//
#include <hip/hip_runtime.h>
#include <hip/hip_bf16.h>
#include <hip/hip_fp16.h>
#include <math.h>

// EdgeNetEMD: BatchNorm(4) -> EdgeConv(8->32->32->2, relu_last) -> EdgeConv(4->32->32->4)
// N=100000 nodes, E=3200000 edges, fp32 in/out.
// Round 6: rank_hist fused into enc_mfma (atomics overlap MFMA work);
// per-edge scratch in fp16 (u=half2, v=half4); segment reduces use 16
// lanes/node with shfl(width=16) tree (coalesced perm reads, 16x TLP).

constexpr int DD  = 4;
constexpr int BIG = 32;
constexpr int HID = 2;

typedef __attribute__((ext_vector_type(8))) short bf16x8;
typedef __attribute__((ext_vector_type(4))) float f32x4;
typedef unsigned int u32;

union frag_u { bf16x8 v; u32 w[4]; };

__device__ inline unsigned short bfbits(float f) {
    __hip_bfloat16 h = __float2bfloat16(f);
    unsigned short s; __builtin_memcpy(&s, &h, 2); return s;
}
__device__ inline u32 pkbf(float lo, float hi) {
    return (u32)bfbits(lo) | ((u32)bfbits(hi) << 16);
}
__device__ inline u32 pkh(float lo, float hi) {
    __half2 h = __floats2half2_rn(lo, hi);
    u32 w; __builtin_memcpy(&w, &h, 4); return w;
}
__device__ inline float2 uph(u32 w) {
    __half2 h; __builtin_memcpy(&h, &w, 4);
    return __half22float2(h);
}

// ---------------- BatchNorm statistics ----------------
__global__ void bn_reduce_kernel(const float* __restrict__ x, int n,
                                 float* __restrict__ sums)
{
    float s0=0.f,s1=0.f,s2=0.f,s3=0.f,q0=0.f,q1=0.f,q2=0.f,q3=0.f;
    int stride = gridDim.x * blockDim.x;
    for (int i = blockIdx.x * blockDim.x + threadIdx.x; i < n; i += stride) {
        float4 v = reinterpret_cast<const float4*>(x)[i];
        s0 += v.x; s1 += v.y; s2 += v.z; s3 += v.w;
        q0 = fmaf(v.x, v.x, q0); q1 = fmaf(v.y, v.y, q1);
        q2 = fmaf(v.z, v.z, q2); q3 = fmaf(v.w, v.w, q3);
    }
    #pragma unroll
    for (int off = 32; off >= 1; off >>= 1) {
        s0 += __shfl_down(s0, off); s1 += __shfl_down(s1, off);
        s2 += __shfl_down(s2, off); s3 += __shfl_down(s3, off);
        q0 += __shfl_down(q0, off); q1 += __shfl_down(q1, off);
        q2 += __shfl_down(q2, off); q3 += __shfl_down(q3, off);
    }
    __shared__ float red[4][8];
    int wave = threadIdx.x >> 6;
    int lane = threadIdx.x & 63;
    if (lane == 0) {
        red[wave][0]=s0; red[wave][1]=s1; red[wave][2]=s2; red[wave][3]=s3;
        red[wave][4]=q0; red[wave][5]=q1; red[wave][6]=q2; red[wave][7]=q3;
    }
    __syncthreads();
    if (threadIdx.x < 8) {
        int nw = blockDim.x >> 6;
        float t = 0.f;
        for (int w = 0; w < nw; ++w) t += red[w][threadIdx.x];
        atomicAdd(&sums[threadIdx.x], t);
    }
}

__global__ void bn_finalize_kernel(const float* __restrict__ sums,
                                   const float* __restrict__ gamma,
                                   const float* __restrict__ beta,
                                   float* __restrict__ ab, float invN)
{
    int f = threadIdx.x;
    if (f < DD) {
        float mean = sums[f] * invN;
        float var  = sums[DD + f] * invN - mean * mean;
        float a = gamma[f] / sqrtf(var + 1e-5f);
        ab[f]      = a;
        ab[DD + f] = beta[f] - mean * a;
    }
}

// ---------------- scan (off = exclusive prefix of deg) ----------------
constexpr int SCAN_CHUNK = 1024;

__global__ __launch_bounds__(256) void scan_block_sums_kernel(const int* __restrict__ deg, int n,
                                                              int* __restrict__ bsum)
{
    int b = blockIdx.x;
    int base = b * SCAN_CHUNK + threadIdx.x * 4;
    int s = 0;
    #pragma unroll
    for (int k = 0; k < 4; ++k) { int i = base + k; if (i < n) s += deg[i]; }
    #pragma unroll
    for (int o = 32; o >= 1; o >>= 1) s += __shfl_down(s, o);
    __shared__ int red[4];
    int wave = threadIdx.x >> 6, lane = threadIdx.x & 63;
    if (lane == 0) red[wave] = s;
    __syncthreads();
    if (threadIdx.x == 0) bsum[b] = red[0] + red[1] + red[2] + red[3];
}

// bsum and bbase MUST be separate buffers (round-2 aliasing fault).
__global__ void scan_base_kernel(const int* bsum, int nb, int* bbase)
{
    if (threadIdx.x == 0) {
        int running = 0;
        for (int b = 0; b < nb; ++b) {
            int v = bsum[b];
            bbase[b] = running;
            running += v;
        }
    }
}

__global__ __launch_bounds__(256) void scan_write_kernel(const int* __restrict__ deg, int n,
                                                         const int* __restrict__ bbase,
                                                         int* __restrict__ off)
{
    int b = blockIdx.x, tid = threadIdx.x;
    int base = b * SCAN_CHUNK + tid * 4;
    int v[4]; int s = 0;
    #pragma unroll
    for (int k = 0; k < 4; ++k) { int i = base + k; v[k] = (i < n) ? deg[i] : 0; s += v[k]; }
    int lane = tid & 63, wave = tid >> 6;
    int inc = s;
    #pragma unroll
    for (int o = 1; o < 64; o <<= 1) { int t = __shfl_up(inc, o); if (lane >= o) inc += t; }
    __shared__ int wsum[4];
    if (lane == 63) wsum[wave] = inc;
    __syncthreads();
    int wbase = 0;
    for (int w = 0; w < wave; ++w) wbase += wsum[w];
    int cur = bbase[b] + wbase + inc - s;
    #pragma unroll
    for (int k = 0; k < 4; ++k) {
        int i = base + k;
        if (i < n) {
            off[i] = cur;
            cur += v[k];
            if (i == n - 1) off[n] = cur;
        }
    }
}

__global__ __launch_bounds__(256) void scatter_perm_kernel(const int* __restrict__ dst,
                                                           const unsigned short* __restrict__ rank,
                                                           const int* __restrict__ off,
                                                           int* __restrict__ perm, int E)
{
    int e = blockIdx.x * 256 + threadIdx.x;
    if (e >= E) return;
    int d = dst[e];
    int idx = off[d] + (int)rank[e];
    idx = min(max(idx, 0), E - 1);
    perm[idx] = e;
}

// ---------------- Encoder per-edge MLP via MFMA + fused rank histogram ----------------
// Per wave, per batch of 16 edges: In^T [K x 16edges], H^T = W^T * In^T.
// k-mapping for A/B fragments: k = 8*(lane>>4) + i (self-consistent A/B).
// C/D layout (HW-verified m89): col = lane&15 (edge), row = 4*(lane>>4)+reg (feat).
// Fused: lanes 0-15 (which load dst[e] anyway) do atomicAdd(deg)+rank store.
__global__ __launch_bounds__(256) void enc_mfma_rank_kernel(
    const float* __restrict__ x, const int* __restrict__ src, const int* __restrict__ dst,
    const float* __restrict__ ab,
    const float* __restrict__ W1, const float* __restrict__ b1,
    const float* __restrict__ W2, const float* __restrict__ b2,
    const float* __restrict__ W3, const float* __restrict__ b3,
    u32* __restrict__ u /* half2 per edge */,
    int* __restrict__ deg, unsigned short* __restrict__ rank,
    int N, int E, int nbatch, int nwaves)
{
    __shared__ __align__(16) char lds_all[4][16 * 80];
    const int tid  = threadIdx.x;
    const int wid  = tid >> 6;
    const int lane = tid & 63;
    const int c    = lane & 15;
    const int g    = lane >> 4;
    char* lds = lds_all[wid];

    // ---- weight fragments (once per kernel) ----
    frag_u A1[2];
    #pragma unroll
    for (int t = 0; t < 2; ++t) {
        A1[t].w[0] = A1[t].w[1] = A1[t].w[2] = A1[t].w[3] = 0;
        if (g == 0) {
            int of = 16 * t + c;
            #pragma unroll
            for (int j = 0; j < 4; ++j)
                A1[t].w[j] = pkbf(W1[(2*j+0)*BIG + of], W1[(2*j+1)*BIG + of]);
        }
    }
    frag_u A2[2];
    #pragma unroll
    for (int t = 0; t < 2; ++t) {
        int of = 16 * t + c;
        #pragma unroll
        for (int j = 0; j < 4; ++j)
            A2[t].w[j] = pkbf(W2[(8*g + 2*j + 0)*BIG + of], W2[(8*g + 2*j + 1)*BIG + of]);
    }
    frag_u A3;
    A3.w[0] = A3.w[1] = A3.w[2] = A3.w[3] = 0;
    if (c < HID) {
        #pragma unroll
        for (int j = 0; j < 4; ++j)
            A3.w[j] = pkbf(W3[(8*g + 2*j + 0)*HID + c], W3[(8*g + 2*j + 1)*HID + c]);
    }
    float4 b1v0 = *reinterpret_cast<const float4*>(b1 + 4*g);
    float4 b1v1 = *reinterpret_cast<const float4*>(b1 + 16 + 4*g);
    float4 b2v0 = *reinterpret_cast<const float4*>(b2 + 4*g);
    float4 b2v1 = *reinterpret_cast<const float4*>(b2 + 16 + 4*g);
    float b30 = b3[0], b31 = b3[1];
    float a0 = ab[0], a1 = ab[1], a2 = ab[2], a3 = ab[3];
    float c0 = ab[4], c1 = ab[5], c2 = ab[6], c3 = ab[7];

    const f32x4 zero4 = {0.f, 0.f, 0.f, 0.f};

    for (int batch = blockIdx.x * 4 + wid; batch < nbatch; batch += nwaves) {
        int ebase = batch * 16;
        int e = min(ebase + c, E - 1);
        bool live = (ebase + c) < E;

        float4 xv = make_float4(0.f, 0.f, 0.f, 0.f);
        if (lane < 32) {
            const int* ip = (lane < 16) ? dst : src;
            int idx = ip[e];
            // fused rank histogram: lanes 0-15 hold dst[e]
            if (lane < 16 && live) {
                int dcl = min(max(idx, 0), N - 1);
                int old = atomicAdd(&deg[dcl], 1);
                rank[e] = (unsigned short)old;
            }
            idx = min(max(idx, 0), N - 1);
            xv = reinterpret_cast<const float4*>(x)[idx];
        }
        float xd0 = __shfl(xv.x, c),      xd1 = __shfl(xv.y, c);
        float xd2 = __shfl(xv.z, c),      xd3 = __shfl(xv.w, c);
        float xs0 = __shfl(xv.x, 16 + c), xs1 = __shfl(xv.y, 16 + c);
        float xs2 = __shfl(xv.z, 16 + c), xs3 = __shfl(xv.w, 16 + c);

        float n0 = fmaf(xd0, a0, c0), n1 = fmaf(xd1, a1, c1);
        float n2 = fmaf(xd2, a2, c2), n3 = fmaf(xd3, a3, c3);
        float d0 = (xs0 - xd0) * a0,  d1 = (xs1 - xd1) * a1;
        float d2 = (xs2 - xd2) * a2,  d3 = (xs3 - xd3) * a3;

        frag_u B1;
        if (g == 0) {
            B1.w[0] = pkbf(n0, n1); B1.w[1] = pkbf(n2, n3);
            B1.w[2] = pkbf(d0, d1); B1.w[3] = pkbf(d2, d3);
        } else {
            B1.w[0] = B1.w[1] = B1.w[2] = B1.w[3] = 0;
        }

        // ---- layer 1 ----
        f32x4 D0 = __builtin_amdgcn_mfma_f32_16x16x32_bf16(A1[0].v, B1.v, zero4, 0, 0, 0);
        f32x4 D1 = __builtin_amdgcn_mfma_f32_16x16x32_bf16(A1[1].v, B1.v, zero4, 0, 0, 0);
        {
            float h0 = fmaxf(D0[0] + b1v0.x, 0.f), h1 = fmaxf(D0[1] + b1v0.y, 0.f);
            float h2 = fmaxf(D0[2] + b1v0.z, 0.f), h3 = fmaxf(D0[3] + b1v0.w, 0.f);
            *reinterpret_cast<uint2*>(lds + c*80 + 8*g) = make_uint2(pkbf(h0, h1), pkbf(h2, h3));
            float k0 = fmaxf(D1[0] + b1v1.x, 0.f), k1 = fmaxf(D1[1] + b1v1.y, 0.f);
            float k2 = fmaxf(D1[2] + b1v1.z, 0.f), k3 = fmaxf(D1[3] + b1v1.w, 0.f);
            *reinterpret_cast<uint2*>(lds + c*80 + 32 + 8*g) = make_uint2(pkbf(k0, k1), pkbf(k2, k3));
        }
        frag_u B2;
        *reinterpret_cast<uint4*>(&B2.w[0]) = *reinterpret_cast<const uint4*>(lds + c*80 + 16*g);

        // ---- layer 2 ----
        f32x4 E0 = __builtin_amdgcn_mfma_f32_16x16x32_bf16(A2[0].v, B2.v, zero4, 0, 0, 0);
        f32x4 E1 = __builtin_amdgcn_mfma_f32_16x16x32_bf16(A2[1].v, B2.v, zero4, 0, 0, 0);
        {
            float h0 = fmaxf(E0[0] + b2v0.x, 0.f), h1 = fmaxf(E0[1] + b2v0.y, 0.f);
            float h2 = fmaxf(E0[2] + b2v0.z, 0.f), h3 = fmaxf(E0[3] + b2v0.w, 0.f);
            *reinterpret_cast<uint2*>(lds + c*80 + 8*g) = make_uint2(pkbf(h0, h1), pkbf(h2, h3));
            float k0 = fmaxf(E1[0] + b2v1.x, 0.f), k1 = fmaxf(E1[1] + b2v1.y, 0.f);
            float k2 = fmaxf(E1[2] + b2v1.z, 0.f), k3 = fmaxf(E1[3] + b2v1.w, 0.f);
            *reinterpret_cast<uint2*>(lds + c*80 + 32 + 8*g) = make_uint2(pkbf(k0, k1), pkbf(k2, k3));
        }
        frag_u B3;
        *reinterpret_cast<uint4*>(&B3.w[0]) = *reinterpret_cast<const uint4*>(lds + c*80 + 16*g);

        // ---- layer 3 ----
        f32x4 F = __builtin_amdgcn_mfma_f32_16x16x32_bf16(A3.v, B3.v, zero4, 0, 0, 0);
        if (lane < 16 && live) {
            float o0 = fmaxf(F[0] + b30, 0.f);
            float o1 = fmaxf(F[1] + b31, 0.f);
            u[ebase + c] = pkh(o0, o1);
        }
    }
}

// ---------------- Decoder per-edge MLP via MFMA ----------------
__global__ __launch_bounds__(256) void dec_mfma_kernel(
    const float* __restrict__ h1n, const int* __restrict__ src, const int* __restrict__ dst,
    const float* __restrict__ W1, const float* __restrict__ b1,
    const float* __restrict__ W2, const float* __restrict__ b2,
    const float* __restrict__ W3, const float* __restrict__ b3,
    uint2* __restrict__ v /* half4 per edge */, int N, int E, int nbatch, int nwaves)
{
    __shared__ __align__(16) char lds_all[4][16 * 80];
    const int tid  = threadIdx.x;
    const int wid  = tid >> 6;
    const int lane = tid & 63;
    const int c    = lane & 15;
    const int g    = lane >> 4;
    char* lds = lds_all[wid];

    frag_u A1[2];
    #pragma unroll
    for (int t = 0; t < 2; ++t) {
        A1[t].w[0] = A1[t].w[1] = A1[t].w[2] = A1[t].w[3] = 0;
        if (g == 0) {
            int of = 16 * t + c;
            A1[t].w[0] = pkbf(W1[0*BIG + of], W1[1*BIG + of]);
            A1[t].w[1] = pkbf(W1[2*BIG + of], W1[3*BIG + of]);
        }
    }
    frag_u A2[2];
    #pragma unroll
    for (int t = 0; t < 2; ++t) {
        int of = 16 * t + c;
        #pragma unroll
        for (int j = 0; j < 4; ++j)
            A2[t].w[j] = pkbf(W2[(8*g + 2*j + 0)*BIG + of], W2[(8*g + 2*j + 1)*BIG + of]);
    }
    frag_u A3;
    A3.w[0] = A3.w[1] = A3.w[2] = A3.w[3] = 0;
    if (c < DD) {
        #pragma unroll
        for (int j = 0; j < 4; ++j)
            A3.w[j] = pkbf(W3[(8*g + 2*j + 0)*DD + c], W3[(8*g + 2*j + 1)*DD + c]);
    }
    float4 b1v0 = *reinterpret_cast<const float4*>(b1 + 4*g);
    float4 b1v1 = *reinterpret_cast<const float4*>(b1 + 16 + 4*g);
    float4 b2v0 = *reinterpret_cast<const float4*>(b2 + 4*g);
    float4 b2v1 = *reinterpret_cast<const float4*>(b2 + 16 + 4*g);
    float b30 = b3[0], b31 = b3[1], b32 = b3[2], b33 = b3[3];

    const f32x4 zero4 = {0.f, 0.f, 0.f, 0.f};

    for (int batch = blockIdx.x * 4 + wid; batch < nbatch; batch += nwaves) {
        int ebase = batch * 16;
        int e = min(ebase + c, E - 1);

        float2 hv = make_float2(0.f, 0.f);
        if (lane < 32) {
            const int* ip = (lane < 16) ? dst : src;
            int idx = ip[e];
            idx = min(max(idx, 0), N - 1);
            hv = reinterpret_cast<const float2*>(h1n)[idx];
        }
        float hd0 = __shfl(hv.x, c),      hd1 = __shfl(hv.y, c);
        float hs0 = __shfl(hv.x, 16 + c), hs1 = __shfl(hv.y, 16 + c);
        float i0 = hd0, i1 = hd1, i2 = hs0 - hd0, i3 = hs1 - hd1;

        frag_u B1;
        if (g == 0) {
            B1.w[0] = pkbf(i0, i1); B1.w[1] = pkbf(i2, i3);
            B1.w[2] = 0; B1.w[3] = 0;
        } else {
            B1.w[0] = B1.w[1] = B1.w[2] = B1.w[3] = 0;
        }

        f32x4 D0 = __builtin_amdgcn_mfma_f32_16x16x32_bf16(A1[0].v, B1.v, zero4, 0, 0, 0);
        f32x4 D1 = __builtin_amdgcn_mfma_f32_16x16x32_bf16(A1[1].v, B1.v, zero4, 0, 0, 0);
        {
            float h0 = fmaxf(D0[0] + b1v0.x, 0.f), h1 = fmaxf(D0[1] + b1v0.y, 0.f);
            float h2 = fmaxf(D0[2] + b1v0.z, 0.f), h3 = fmaxf(D0[3] + b1v0.w, 0.f);
            *reinterpret_cast<uint2*>(lds + c*80 + 8*g) = make_uint2(pkbf(h0, h1), pkbf(h2, h3));
            float k0 = fmaxf(D1[0] + b1v1.x, 0.f), k1 = fmaxf(D1[1] + b1v1.y, 0.f);
            float k2 = fmaxf(D1[2] + b1v1.z, 0.f), k3 = fmaxf(D1[3] + b1v1.w, 0.f);
            *reinterpret_cast<uint2*>(lds + c*80 + 32 + 8*g) = make_uint2(pkbf(k0, k1), pkbf(k2, k3));
        }
        frag_u B2;
        *reinterpret_cast<uint4*>(&B2.w[0]) = *reinterpret_cast<const uint4*>(lds + c*80 + 16*g);

        f32x4 E0 = __builtin_amdgcn_mfma_f32_16x16x32_bf16(A2[0].v, B2.v, zero4, 0, 0, 0);
        f32x4 E1 = __builtin_amdgcn_mfma_f32_16x16x32_bf16(A2[1].v, B2.v, zero4, 0, 0, 0);
        {
            float h0 = fmaxf(E0[0] + b2v0.x, 0.f), h1 = fmaxf(E0[1] + b2v0.y, 0.f);
            float h2 = fmaxf(E0[2] + b2v0.z, 0.f), h3 = fmaxf(E0[3] + b2v0.w, 0.f);
            *reinterpret_cast<uint2*>(lds + c*80 + 8*g) = make_uint2(pkbf(h0, h1), pkbf(h2, h3));
            float k0 = fmaxf(E1[0] + b2v1.x, 0.f), k1 = fmaxf(E1[1] + b2v1.y, 0.f);
            float k2 = fmaxf(E1[2] + b2v1.z, 0.f), k3 = fmaxf(E1[3] + b2v1.w, 0.f);
            *reinterpret_cast<uint2*>(lds + c*80 + 32 + 8*g) = make_uint2(pkbf(k0, k1), pkbf(k2, k3));
        }
        frag_u B3;
        *reinterpret_cast<uint4*>(&B3.w[0]) = *reinterpret_cast<const uint4*>(lds + c*80 + 16*g);

        f32x4 F = __builtin_amdgcn_mfma_f32_16x16x32_bf16(A3.v, B3.v, zero4, 0, 0, 0);
        if (lane < 16 && (ebase + c) < E) {
            uint2 o;
            o.x = pkh(F[0] + b30, F[1] + b31);
            o.y = pkh(F[2] + b32, F[3] + b33);
            v[ebase + c] = o;
        }
    }
}

// ---------------- segment reduces: 16 lanes per node ----------------
__global__ __launch_bounds__(256) void enc_reduce16_kernel(
    const u32* __restrict__ u, const int* __restrict__ perm, const int* __restrict__ off,
    float* __restrict__ h1, int N, int E)
{
    int gt  = blockIdx.x * 256 + threadIdx.x;
    int i   = gt >> 4;
    int sub = gt & 15;
    if (i >= N) return;
    int beg = off[i], end = off[i + 1];
    float acc0 = 0.f, acc1 = 0.f;
    for (int p = beg + sub; p < end; p += 16) {
        int e = perm[p];
        e = min(max(e, 0), E - 1);
        float2 t = uph(u[e]);
        acc0 += t.x; acc1 += t.y;
    }
    #pragma unroll
    for (int o = 8; o >= 1; o >>= 1) {
        acc0 += __shfl_down(acc0, o, 16);
        acc1 += __shfl_down(acc1, o, 16);
    }
    if (sub == 0) {
        float inv = 1.0f / fmaxf((float)(end - beg), 1.0f);
        float2 o; o.x = acc0 * inv; o.y = acc1 * inv;
        reinterpret_cast<float2*>(h1)[i] = o;
    }
}

__global__ __launch_bounds__(256) void dec_reduce16_kernel(
    const uint2* __restrict__ v, const int* __restrict__ perm, const int* __restrict__ off,
    float* __restrict__ out, int N, int E)
{
    int gt  = blockIdx.x * 256 + threadIdx.x;
    int i   = gt >> 4;
    int sub = gt & 15;
    if (i >= N) return;
    int beg = off[i], end = off[i + 1];
    float acc0 = 0.f, acc1 = 0.f, acc2 = 0.f, acc3 = 0.f;
    for (int p = beg + sub; p < end; p += 16) {
        int e = perm[p];
        e = min(max(e, 0), E - 1);
        uint2 w = v[e];
        float2 t0 = uph(w.x), t1 = uph(w.y);
        acc0 += t0.x; acc1 += t0.y; acc2 += t1.x; acc3 += t1.y;
    }
    #pragma unroll
    for (int o = 8; o >= 1; o >>= 1) {
        acc0 += __shfl_down(acc0, o, 16);
        acc1 += __shfl_down(acc1, o, 16);
        acc2 += __shfl_down(acc2, o, 16);
        acc3 += __shfl_down(acc3, o, 16);
    }
    if (sub == 0) {
        float inv = 1.0f / fmaxf((float)(end - beg), 1.0f);
        float4 o;
        o.x = acc0 * inv; o.y = acc1 * inv; o.z = acc2 * inv; o.w = acc3 * inv;
        reinterpret_cast<float4*>(out)[i] = o;
    }
}

// ---------------- Fallback (round-1 atomic path) ----------------
__global__ __launch_bounds__(256) void enc_edge_kernel(
    const float* __restrict__ x, const int* __restrict__ src, const int* __restrict__ dst,
    const float* __restrict__ ab,
    const float* __restrict__ W1, const float* __restrict__ b1,
    const float* __restrict__ W2, const float* __restrict__ b2,
    const float* __restrict__ W3, const float* __restrict__ b3,
    float* __restrict__ acc, float* __restrict__ cnt, int E)
{
    int e = blockIdx.x * blockDim.x + threadIdx.x;
    if (e >= E) return;
    int si = src[e];
    int di = dst[e];
    float4 xd = reinterpret_cast<const float4*>(x)[di];
    float4 xs = reinterpret_cast<const float4*>(x)[si];
    float a0 = ab[0], a1 = ab[1], a2 = ab[2], a3 = ab[3];
    float c0 = ab[4], c1 = ab[5], c2 = ab[6], c3 = ab[7];
    float in[2 * DD];
    in[0] = fmaf(xd.x, a0, c0); in[1] = fmaf(xd.y, a1, c1);
    in[2] = fmaf(xd.z, a2, c2); in[3] = fmaf(xd.w, a3, c3);
    in[4] = (xs.x - xd.x) * a0; in[5] = (xs.y - xd.y) * a1;
    in[6] = (xs.z - xd.z) * a2; in[7] = (xs.w - xd.w) * a3;
    float h[BIG];
    #pragma unroll
    for (int j = 0; j < BIG; ++j) {
        float t = b1[j];
        #pragma unroll
        for (int k = 0; k < 2 * DD; ++k) t = fmaf(in[k], W1[k * BIG + j], t);
        h[j] = fmaxf(t, 0.0f);
    }
    float g[BIG];
    #pragma unroll
    for (int j = 0; j < BIG; ++j) {
        float t = b2[j];
        #pragma unroll
        for (int k = 0; k < BIG; ++k) t = fmaf(h[k], W2[k * BIG + j], t);
        g[j] = fmaxf(t, 0.0f);
    }
    float u0 = b3[0], u1 = b3[1];
    #pragma unroll
    for (int k = 0; k < BIG; ++k) {
        u0 = fmaf(g[k], W3[k * HID + 0], u0);
        u1 = fmaf(g[k], W3[k * HID + 1], u1);
    }
    atomicAdd(&acc[di * HID + 0], fmaxf(u0, 0.0f));
    atomicAdd(&acc[di * HID + 1], fmaxf(u1, 0.0f));
    atomicAdd(&cnt[di], 1.0f);
}

__global__ void finalize_h1_kernel(float* __restrict__ acc, const float* __restrict__ cnt, int n)
{
    int i = blockIdx.x * blockDim.x + threadIdx.x;
    if (i >= n) return;
    float inv = 1.0f / fmaxf(cnt[i], 1.0f);
    acc[i * HID + 0] *= inv;
    acc[i * HID + 1] *= inv;
}

__global__ __launch_bounds__(256) void dec_edge_kernel(
    const float* __restrict__ h1, const int* __restrict__ src, const int* __restrict__ dst,
    const float* __restrict__ W1, const float* __restrict__ b1,
    const float* __restrict__ W2, const float* __restrict__ b2,
    const float* __restrict__ W3, const float* __restrict__ b3,
    float* __restrict__ out, int E)
{
    int e = blockIdx.x * blockDim.x + threadIdx.x;
    if (e >= E) return;
    int si = src[e];
    int di = dst[e];
    float2 hd = reinterpret_cast<const float2*>(h1)[di];
    float2 hs = reinterpret_cast<const float2*>(h1)[si];
    float in[2 * HID];
    in[0] = hd.x; in[1] = hd.y;
    in[2] = hs.x - hd.x; in[3] = hs.y - hd.y;
    float h[BIG];
    #pragma unroll
    for (int j = 0; j < BIG; ++j) {
        float t = b1[j];
        #pragma unroll
        for (int k = 0; k < 2 * HID; ++k) t = fmaf(in[k], W1[k * BIG + j], t);
        h[j] = fmaxf(t, 0.0f);
    }
    float g[BIG];
    #pragma unroll
    for (int j = 0; j < BIG; ++j) {
        float t = b2[j];
        #pragma unroll
        for (int k = 0; k < BIG; ++k) t = fmaf(h[k], W2[k * BIG + j], t);
        g[j] = fmaxf(t, 0.0f);
    }
    float u0 = b3[0], u1 = b3[1], u2 = b3[2], u3 = b3[3];
    #pragma unroll
    for (int k = 0; k < BIG; ++k) {
        u0 = fmaf(g[k], W3[k * DD + 0], u0);
        u1 = fmaf(g[k], W3[k * DD + 1], u1);
        u2 = fmaf(g[k], W3[k * DD + 2], u2);
        u3 = fmaf(g[k], W3[k * DD + 3], u3);
    }
    atomicAdd(&out[di * DD + 0], u0);
    atomicAdd(&out[di * DD + 1], u1);
    atomicAdd(&out[di * DD + 2], u2);
    atomicAdd(&out[di * DD + 3], u3);
}

__global__ void finalize_out_kernel(float* __restrict__ out, const float* __restrict__ cnt, int n)
{
    int i = blockIdx.x * blockDim.x + threadIdx.x;
    if (i >= n) return;
    float inv = 1.0f / fmaxf(cnt[i], 1.0f);
    float4 v = reinterpret_cast<float4*>(out)[i];
    v.x *= inv; v.y *= inv; v.z *= inv; v.w *= inv;
    reinterpret_cast<float4*>(out)[i] = v;
}

// ---------------- launch ----------------
extern "C" void kernel_launch(void* const* d_in, const int* in_sizes, int n_in,
                              void* d_out, int out_size, void* d_ws, size_t ws_size,
                              hipStream_t stream)
{
    const float* x     = (const float*)d_in[0];
    const int*   src   = (const int*)  d_in[1];
    const int*   dst   = (const int*)  d_in[2];
    const float* gamma = (const float*)d_in[3];
    const float* beta  = (const float*)d_in[4];
    const float* eW1 = (const float*)d_in[5];  const float* eb1 = (const float*)d_in[6];
    const float* eW2 = (const float*)d_in[7];  const float* eb2 = (const float*)d_in[8];
    const float* eW3 = (const float*)d_in[9];  const float* eb3 = (const float*)d_in[10];
    const float* dW1 = (const float*)d_in[11]; const float* db1 = (const float*)d_in[12];
    const float* dW2 = (const float*)d_in[13]; const float* db2 = (const float*)d_in[14];
    const float* dW3 = (const float*)d_in[15]; const float* db3 = (const float*)d_in[16];

    const int N = in_sizes[0] / DD;
    const int E = in_sizes[1];
    float* out = (float*)d_out;

    auto rnd16 = [](size_t b) { return (b + 15) & ~(size_t)15; };
    size_t need = 0;
    size_t o_sums  = need; need += rnd16(8 * 4);
    size_t o_ab    = need; need += rnd16(8 * 4);
    size_t o_bsum  = need; need += rnd16(256 * 4);
    size_t o_bbase = need; need += rnd16(256 * 4);
    size_t o_deg   = need; need += rnd16((size_t)N * 4);
    size_t o_off   = need; need += rnd16((size_t)(N + 1) * 4);
    size_t o_h1    = need; need += rnd16((size_t)2 * N * 4);
    size_t o_perm  = need; need += rnd16((size_t)E * 4);
    size_t o_rank  = need; need += rnd16((size_t)E * 2);
    size_t o_u     = need; need += rnd16((size_t)E * 4);   // half2 per edge
    size_t o_v     = need; need += rnd16((size_t)E * 8);   // half4 per edge

    char* wsb = (char*)d_ws;

    if (ws_size >= need && N > 0 && E > 0) {
        float*          sums  = (float*)(wsb + o_sums);
        float*          ab    = (float*)(wsb + o_ab);
        int*            bsum  = (int*)  (wsb + o_bsum);
        int*            bbase = (int*)  (wsb + o_bbase);
        int*            deg   = (int*)  (wsb + o_deg);
        int*            off   = (int*)  (wsb + o_off);
        float*          h1    = (float*)(wsb + o_h1);
        int*            perm  = (int*)  (wsb + o_perm);
        unsigned short* rank  = (unsigned short*)(wsb + o_rank);
        u32*            u     = (u32*)  (wsb + o_u);
        uint2*          v     = (uint2*)(wsb + o_v);

        hipMemsetAsync(sums, 0, 8 * sizeof(float), stream);
        hipMemsetAsync(deg, 0, (size_t)N * sizeof(int), stream);

        bn_reduce_kernel<<<256, 256, 0, stream>>>(x, N, sums);
        bn_finalize_kernel<<<1, 64, 0, stream>>>(sums, gamma, beta, ab, 1.0f / (float)N);

        int eblocks = (E + 255) / 256;
        int nbatch = (E + 15) / 16;
        int mblocks = 1024;
        int nwaves = mblocks * 4;

        // fused: MLP (MFMA) + rank histogram + u (half2) store
        enc_mfma_rank_kernel<<<mblocks, 256, 0, stream>>>(x, src, dst, ab,
                                                          eW1, eb1, eW2, eb2, eW3, eb3,
                                                          u, deg, rank, N, E, nbatch, nwaves);

        int nb = (N + SCAN_CHUNK - 1) / SCAN_CHUNK;
        scan_block_sums_kernel<<<nb, 256, 0, stream>>>(deg, N, bsum);
        scan_base_kernel<<<1, 64, 0, stream>>>(bsum, nb, bbase);
        scan_write_kernel<<<nb, 256, 0, stream>>>(deg, N, bbase, off);

        scatter_perm_kernel<<<eblocks, 256, 0, stream>>>(dst, rank, off, perm, E);

        int rblocks = ((N * 16) + 255) / 256;
        enc_reduce16_kernel<<<rblocks, 256, 0, stream>>>(u, perm, off, h1, N, E);

        dec_mfma_kernel<<<mblocks, 256, 0, stream>>>(h1, src, dst,
                                                     dW1, db1, dW2, db2, dW3, db3,
                                                     v, N, E, nbatch, nwaves);
        dec_reduce16_kernel<<<rblocks, 256, 0, stream>>>(v, perm, off, out, N, E);
    } else {
        float* ws   = (float*)d_ws;
        float* sums = ws;
        float* ab   = ws + 8;
        float* cnt  = ws + 16;
        float* acc1 = ws + 16 + N;

        hipMemsetAsync(sums, 0, 16 * sizeof(float), stream);
        hipMemsetAsync(cnt, 0, (size_t)(3 * N) * sizeof(float), stream);
        hipMemsetAsync(out, 0, (size_t)out_size * sizeof(float), stream);

        bn_reduce_kernel<<<256, 256, 0, stream>>>(x, N, sums);
        bn_finalize_kernel<<<1, 64, 0, stream>>>(sums, gamma, beta, ab, 1.0f / (float)N);

        int eblocks = (E + 255) / 256;
        enc_edge_kernel<<<eblocks, 256, 0, stream>>>(x, src, dst, ab,
                                                     eW1, eb1, eW2, eb2, eW3, eb3,
                                                     acc1, cnt, E);
        finalize_h1_kernel<<<(N + 255) / 256, 256, 0, stream>>>(acc1, cnt, N);
        dec_edge_kernel<<<eblocks, 256, 0, stream>>>(acc1, src, dst,
                                                     dW1, db1, dW2, db2, dW3, db3,
                                                     out, E);
        finalize_out_kernel<<<(N + 255) / 256, 256, 0, stream>>>(out, cnt, N);
    }
}

// Round 7
// 347.085 us; speedup vs baseline: 11.6172x; 1.0616x over previous
//
#include <hip/hip_runtime.h>
#include <hip/hip_bf16.h>
#include <hip/hip_fp16.h>
#include <math.h>

// EdgeNetEMD: BatchNorm(4) -> EdgeConv(8->32->32->2, relu_last) -> EdgeConv(4->32->32->4)
// N=100000 nodes, E=3200000 edges, fp32 in/out.
// Round 7: no perm. scatter_csr places payloads (sd = {src,dst}, us = u) into
// CSR order once; enc_reduce/dec_reduce stream contiguously; dec_mfma runs in
// CSR slot order (dst-sorted -> gather locality, coalesced writes).
// enc_mfma_rank (atomic histogram fused w/ MFMA MLP) unchanged: it sits at the
// measured ~22-25 G atomics/s device rate (~128 us floor for 3.2M ops).

constexpr int DD  = 4;
constexpr int BIG = 32;
constexpr int HID = 2;

typedef __attribute__((ext_vector_type(8))) short bf16x8;
typedef __attribute__((ext_vector_type(4))) float f32x4;
typedef unsigned int u32;

union frag_u { bf16x8 v; u32 w[4]; };

__device__ inline unsigned short bfbits(float f) {
    __hip_bfloat16 h = __float2bfloat16(f);
    unsigned short s; __builtin_memcpy(&s, &h, 2); return s;
}
__device__ inline u32 pkbf(float lo, float hi) {
    return (u32)bfbits(lo) | ((u32)bfbits(hi) << 16);
}
__device__ inline u32 pkh(float lo, float hi) {
    __half2 h = __floats2half2_rn(lo, hi);
    u32 w; __builtin_memcpy(&w, &h, 4); return w;
}
__device__ inline float2 uph(u32 w) {
    __half2 h; __builtin_memcpy(&h, &w, 4);
    return __half22float2(h);
}

// ---------------- BatchNorm statistics ----------------
__global__ void bn_reduce_kernel(const float* __restrict__ x, int n,
                                 float* __restrict__ sums)
{
    float s0=0.f,s1=0.f,s2=0.f,s3=0.f,q0=0.f,q1=0.f,q2=0.f,q3=0.f;
    int stride = gridDim.x * blockDim.x;
    for (int i = blockIdx.x * blockDim.x + threadIdx.x; i < n; i += stride) {
        float4 v = reinterpret_cast<const float4*>(x)[i];
        s0 += v.x; s1 += v.y; s2 += v.z; s3 += v.w;
        q0 = fmaf(v.x, v.x, q0); q1 = fmaf(v.y, v.y, q1);
        q2 = fmaf(v.z, v.z, q2); q3 = fmaf(v.w, v.w, q3);
    }
    #pragma unroll
    for (int off = 32; off >= 1; off >>= 1) {
        s0 += __shfl_down(s0, off); s1 += __shfl_down(s1, off);
        s2 += __shfl_down(s2, off); s3 += __shfl_down(s3, off);
        q0 += __shfl_down(q0, off); q1 += __shfl_down(q1, off);
        q2 += __shfl_down(q2, off); q3 += __shfl_down(q3, off);
    }
    __shared__ float red[4][8];
    int wave = threadIdx.x >> 6;
    int lane = threadIdx.x & 63;
    if (lane == 0) {
        red[wave][0]=s0; red[wave][1]=s1; red[wave][2]=s2; red[wave][3]=s3;
        red[wave][4]=q0; red[wave][5]=q1; red[wave][6]=q2; red[wave][7]=q3;
    }
    __syncthreads();
    if (threadIdx.x < 8) {
        int nw = blockDim.x >> 6;
        float t = 0.f;
        for (int w = 0; w < nw; ++w) t += red[w][threadIdx.x];
        atomicAdd(&sums[threadIdx.x], t);
    }
}

__global__ void bn_finalize_kernel(const float* __restrict__ sums,
                                   const float* __restrict__ gamma,
                                   const float* __restrict__ beta,
                                   float* __restrict__ ab, float invN)
{
    int f = threadIdx.x;
    if (f < DD) {
        float mean = sums[f] * invN;
        float var  = sums[DD + f] * invN - mean * mean;
        float a = gamma[f] / sqrtf(var + 1e-5f);
        ab[f]      = a;
        ab[DD + f] = beta[f] - mean * a;
    }
}

// ---------------- scan (off = exclusive prefix of deg) ----------------
constexpr int SCAN_CHUNK = 1024;

__global__ __launch_bounds__(256) void scan_block_sums_kernel(const int* __restrict__ deg, int n,
                                                              int* __restrict__ bsum)
{
    int b = blockIdx.x;
    int base = b * SCAN_CHUNK + threadIdx.x * 4;
    int s = 0;
    #pragma unroll
    for (int k = 0; k < 4; ++k) { int i = base + k; if (i < n) s += deg[i]; }
    #pragma unroll
    for (int o = 32; o >= 1; o >>= 1) s += __shfl_down(s, o);
    __shared__ int red[4];
    int wave = threadIdx.x >> 6, lane = threadIdx.x & 63;
    if (lane == 0) red[wave] = s;
    __syncthreads();
    if (threadIdx.x == 0) bsum[b] = red[0] + red[1] + red[2] + red[3];
}

// bsum and bbase MUST be separate buffers (round-2 aliasing fault).
__global__ void scan_base_kernel(const int* bsum, int nb, int* bbase)
{
    if (threadIdx.x == 0) {
        int running = 0;
        for (int b = 0; b < nb; ++b) {
            int v = bsum[b];
            bbase[b] = running;
            running += v;
        }
    }
}

__global__ __launch_bounds__(256) void scan_write_kernel(const int* __restrict__ deg, int n,
                                                         const int* __restrict__ bbase,
                                                         int* __restrict__ off)
{
    int b = blockIdx.x, tid = threadIdx.x;
    int base = b * SCAN_CHUNK + tid * 4;
    int v[4]; int s = 0;
    #pragma unroll
    for (int k = 0; k < 4; ++k) { int i = base + k; v[k] = (i < n) ? deg[i] : 0; s += v[k]; }
    int lane = tid & 63, wave = tid >> 6;
    int inc = s;
    #pragma unroll
    for (int o = 1; o < 64; o <<= 1) { int t = __shfl_up(inc, o); if (lane >= o) inc += t; }
    __shared__ int wsum[4];
    if (lane == 63) wsum[wave] = inc;
    __syncthreads();
    int wbase = 0;
    for (int w = 0; w < wave; ++w) wbase += wsum[w];
    int cur = bbase[b] + wbase + inc - s;
    #pragma unroll
    for (int k = 0; k < 4; ++k) {
        int i = base + k;
        if (i < n) {
            off[i] = cur;
            cur += v[k];
            if (i == n - 1) off[n] = cur;
        }
    }
}

// ---------------- scatter payloads into CSR order ----------------
// sd[idx] = {src[e], dst[e]}, us[idx] = u[e]   with idx = off[dst]+rank (bijective).
__global__ __launch_bounds__(256) void scatter_csr_kernel(const int* __restrict__ src,
                                                          const int* __restrict__ dst,
                                                          const unsigned short* __restrict__ rank,
                                                          const int* __restrict__ off,
                                                          const u32* __restrict__ u,
                                                          int2* __restrict__ sd,
                                                          u32* __restrict__ us, int E)
{
    int e = blockIdx.x * 256 + threadIdx.x;
    if (e >= E) return;
    int d = dst[e];
    int idx = off[d] + (int)rank[e];
    idx = min(max(idx, 0), E - 1);   // safety clamp (wrong value beats a fault)
    sd[idx] = make_int2(src[e], d);
    us[idx] = u[e];
}

// ---------------- Encoder per-edge MLP via MFMA + fused rank histogram ----------------
// Per wave, per batch of 16 edges: In^T [K x 16edges], H^T = W^T * In^T.
// k-mapping for A/B fragments: k = 8*(lane>>4) + i (self-consistent A/B).
// C/D layout (HW-verified m89): col = lane&15 (edge), row = 4*(lane>>4)+reg (feat).
// Fused: lanes 0-15 (which load dst[e] anyway) do atomicAdd(deg)+rank store.
__global__ __launch_bounds__(256) void enc_mfma_rank_kernel(
    const float* __restrict__ x, const int* __restrict__ src, const int* __restrict__ dst,
    const float* __restrict__ ab,
    const float* __restrict__ W1, const float* __restrict__ b1,
    const float* __restrict__ W2, const float* __restrict__ b2,
    const float* __restrict__ W3, const float* __restrict__ b3,
    u32* __restrict__ u /* half2 per edge */,
    int* __restrict__ deg, unsigned short* __restrict__ rank,
    int N, int E, int nbatch, int nwaves)
{
    __shared__ __align__(16) char lds_all[4][16 * 80];
    const int tid  = threadIdx.x;
    const int wid  = tid >> 6;
    const int lane = tid & 63;
    const int c    = lane & 15;
    const int g    = lane >> 4;
    char* lds = lds_all[wid];

    // ---- weight fragments (once per kernel) ----
    frag_u A1[2];
    #pragma unroll
    for (int t = 0; t < 2; ++t) {
        A1[t].w[0] = A1[t].w[1] = A1[t].w[2] = A1[t].w[3] = 0;
        if (g == 0) {
            int of = 16 * t + c;
            #pragma unroll
            for (int j = 0; j < 4; ++j)
                A1[t].w[j] = pkbf(W1[(2*j+0)*BIG + of], W1[(2*j+1)*BIG + of]);
        }
    }
    frag_u A2[2];
    #pragma unroll
    for (int t = 0; t < 2; ++t) {
        int of = 16 * t + c;
        #pragma unroll
        for (int j = 0; j < 4; ++j)
            A2[t].w[j] = pkbf(W2[(8*g + 2*j + 0)*BIG + of], W2[(8*g + 2*j + 1)*BIG + of]);
    }
    frag_u A3;
    A3.w[0] = A3.w[1] = A3.w[2] = A3.w[3] = 0;
    if (c < HID) {
        #pragma unroll
        for (int j = 0; j < 4; ++j)
            A3.w[j] = pkbf(W3[(8*g + 2*j + 0)*HID + c], W3[(8*g + 2*j + 1)*HID + c]);
    }
    float4 b1v0 = *reinterpret_cast<const float4*>(b1 + 4*g);
    float4 b1v1 = *reinterpret_cast<const float4*>(b1 + 16 + 4*g);
    float4 b2v0 = *reinterpret_cast<const float4*>(b2 + 4*g);
    float4 b2v1 = *reinterpret_cast<const float4*>(b2 + 16 + 4*g);
    float b30 = b3[0], b31 = b3[1];
    float a0 = ab[0], a1 = ab[1], a2 = ab[2], a3 = ab[3];
    float c0 = ab[4], c1 = ab[5], c2 = ab[6], c3 = ab[7];

    const f32x4 zero4 = {0.f, 0.f, 0.f, 0.f};

    for (int batch = blockIdx.x * 4 + wid; batch < nbatch; batch += nwaves) {
        int ebase = batch * 16;
        int e = min(ebase + c, E - 1);
        bool live = (ebase + c) < E;

        float4 xv = make_float4(0.f, 0.f, 0.f, 0.f);
        if (lane < 32) {
            const int* ip = (lane < 16) ? dst : src;
            int idx = ip[e];
            // fused rank histogram: lanes 0-15 hold dst[e]
            if (lane < 16 && live) {
                int dcl = min(max(idx, 0), N - 1);
                int old = atomicAdd(&deg[dcl], 1);
                rank[e] = (unsigned short)old;
            }
            idx = min(max(idx, 0), N - 1);
            xv = reinterpret_cast<const float4*>(x)[idx];
        }
        float xd0 = __shfl(xv.x, c),      xd1 = __shfl(xv.y, c);
        float xd2 = __shfl(xv.z, c),      xd3 = __shfl(xv.w, c);
        float xs0 = __shfl(xv.x, 16 + c), xs1 = __shfl(xv.y, 16 + c);
        float xs2 = __shfl(xv.z, 16 + c), xs3 = __shfl(xv.w, 16 + c);

        float n0 = fmaf(xd0, a0, c0), n1 = fmaf(xd1, a1, c1);
        float n2 = fmaf(xd2, a2, c2), n3 = fmaf(xd3, a3, c3);
        float d0 = (xs0 - xd0) * a0,  d1 = (xs1 - xd1) * a1;
        float d2 = (xs2 - xd2) * a2,  d3 = (xs3 - xd3) * a3;

        frag_u B1;
        if (g == 0) {
            B1.w[0] = pkbf(n0, n1); B1.w[1] = pkbf(n2, n3);
            B1.w[2] = pkbf(d0, d1); B1.w[3] = pkbf(d2, d3);
        } else {
            B1.w[0] = B1.w[1] = B1.w[2] = B1.w[3] = 0;
        }

        // ---- layer 1 ----
        f32x4 D0 = __builtin_amdgcn_mfma_f32_16x16x32_bf16(A1[0].v, B1.v, zero4, 0, 0, 0);
        f32x4 D1 = __builtin_amdgcn_mfma_f32_16x16x32_bf16(A1[1].v, B1.v, zero4, 0, 0, 0);
        {
            float h0 = fmaxf(D0[0] + b1v0.x, 0.f), h1 = fmaxf(D0[1] + b1v0.y, 0.f);
            float h2 = fmaxf(D0[2] + b1v0.z, 0.f), h3 = fmaxf(D0[3] + b1v0.w, 0.f);
            *reinterpret_cast<uint2*>(lds + c*80 + 8*g) = make_uint2(pkbf(h0, h1), pkbf(h2, h3));
            float k0 = fmaxf(D1[0] + b1v1.x, 0.f), k1 = fmaxf(D1[1] + b1v1.y, 0.f);
            float k2 = fmaxf(D1[2] + b1v1.z, 0.f), k3 = fmaxf(D1[3] + b1v1.w, 0.f);
            *reinterpret_cast<uint2*>(lds + c*80 + 32 + 8*g) = make_uint2(pkbf(k0, k1), pkbf(k2, k3));
        }
        frag_u B2;
        *reinterpret_cast<uint4*>(&B2.w[0]) = *reinterpret_cast<const uint4*>(lds + c*80 + 16*g);

        // ---- layer 2 ----
        f32x4 E0 = __builtin_amdgcn_mfma_f32_16x16x32_bf16(A2[0].v, B2.v, zero4, 0, 0, 0);
        f32x4 E1 = __builtin_amdgcn_mfma_f32_16x16x32_bf16(A2[1].v, B2.v, zero4, 0, 0, 0);
        {
            float h0 = fmaxf(E0[0] + b2v0.x, 0.f), h1 = fmaxf(E0[1] + b2v0.y, 0.f);
            float h2 = fmaxf(E0[2] + b2v0.z, 0.f), h3 = fmaxf(E0[3] + b2v0.w, 0.f);
            *reinterpret_cast<uint2*>(lds + c*80 + 8*g) = make_uint2(pkbf(h0, h1), pkbf(h2, h3));
            float k0 = fmaxf(E1[0] + b2v1.x, 0.f), k1 = fmaxf(E1[1] + b2v1.y, 0.f);
            float k2 = fmaxf(E1[2] + b2v1.z, 0.f), k3 = fmaxf(E1[3] + b2v1.w, 0.f);
            *reinterpret_cast<uint2*>(lds + c*80 + 32 + 8*g) = make_uint2(pkbf(k0, k1), pkbf(k2, k3));
        }
        frag_u B3;
        *reinterpret_cast<uint4*>(&B3.w[0]) = *reinterpret_cast<const uint4*>(lds + c*80 + 16*g);

        // ---- layer 3 ----
        f32x4 F = __builtin_amdgcn_mfma_f32_16x16x32_bf16(A3.v, B3.v, zero4, 0, 0, 0);
        if (lane < 16 && live) {
            float o0 = fmaxf(F[0] + b30, 0.f);
            float o1 = fmaxf(F[1] + b31, 0.f);
            u[ebase + c] = pkh(o0, o1);
        }
    }
}

// ---------------- Decoder per-edge MLP via MFMA, CSR slot order ----------------
// Slot p: sd[p] = {src, dst}; in = [h1[dst], h1[src]-h1[dst]]; vs[p] = out (half4).
// dst-sorted slots -> h1[dst] gathers are runs of the same index (L1/L2 hits);
// sd reads and vs writes fully coalesced.
__global__ __launch_bounds__(256) void dec_mfma_kernel(
    const float* __restrict__ h1n, const int2* __restrict__ sd,
    const float* __restrict__ W1, const float* __restrict__ b1,
    const float* __restrict__ W2, const float* __restrict__ b2,
    const float* __restrict__ W3, const float* __restrict__ b3,
    uint2* __restrict__ vs /* half4 per slot */, int N, int E, int nbatch, int nwaves)
{
    __shared__ __align__(16) char lds_all[4][16 * 80];
    const int tid  = threadIdx.x;
    const int wid  = tid >> 6;
    const int lane = tid & 63;
    const int c    = lane & 15;
    const int g    = lane >> 4;
    char* lds = lds_all[wid];

    frag_u A1[2];
    #pragma unroll
    for (int t = 0; t < 2; ++t) {
        A1[t].w[0] = A1[t].w[1] = A1[t].w[2] = A1[t].w[3] = 0;
        if (g == 0) {
            int of = 16 * t + c;
            A1[t].w[0] = pkbf(W1[0*BIG + of], W1[1*BIG + of]);
            A1[t].w[1] = pkbf(W1[2*BIG + of], W1[3*BIG + of]);
        }
    }
    frag_u A2[2];
    #pragma unroll
    for (int t = 0; t < 2; ++t) {
        int of = 16 * t + c;
        #pragma unroll
        for (int j = 0; j < 4; ++j)
            A2[t].w[j] = pkbf(W2[(8*g + 2*j + 0)*BIG + of], W2[(8*g + 2*j + 1)*BIG + of]);
    }
    frag_u A3;
    A3.w[0] = A3.w[1] = A3.w[2] = A3.w[3] = 0;
    if (c < DD) {
        #pragma unroll
        for (int j = 0; j < 4; ++j)
            A3.w[j] = pkbf(W3[(8*g + 2*j + 0)*DD + c], W3[(8*g + 2*j + 1)*DD + c]);
    }
    float4 b1v0 = *reinterpret_cast<const float4*>(b1 + 4*g);
    float4 b1v1 = *reinterpret_cast<const float4*>(b1 + 16 + 4*g);
    float4 b2v0 = *reinterpret_cast<const float4*>(b2 + 4*g);
    float4 b2v1 = *reinterpret_cast<const float4*>(b2 + 16 + 4*g);
    float b30 = b3[0], b31 = b3[1], b32 = b3[2], b33 = b3[3];

    const f32x4 zero4 = {0.f, 0.f, 0.f, 0.f};

    for (int batch = blockIdx.x * 4 + wid; batch < nbatch; batch += nwaves) {
        int pbase = batch * 16;
        int p = min(pbase + c, E - 1);

        int2 sdv = make_int2(0, 0);
        if (lane < 16) sdv = sd[p];
        int dv = __shfl(sdv.y, c);   // dst of slot c
        int sv = __shfl(sdv.x, c);   // src of slot c

        float2 hv = make_float2(0.f, 0.f);
        if (lane < 32) {
            int idx = (lane < 16) ? dv : sv;
            idx = min(max(idx, 0), N - 1);
            hv = reinterpret_cast<const float2*>(h1n)[idx];
        }
        float hd0 = __shfl(hv.x, c),      hd1 = __shfl(hv.y, c);
        float hs0 = __shfl(hv.x, 16 + c), hs1 = __shfl(hv.y, 16 + c);
        float i0 = hd0, i1 = hd1, i2 = hs0 - hd0, i3 = hs1 - hd1;

        frag_u B1;
        if (g == 0) {
            B1.w[0] = pkbf(i0, i1); B1.w[1] = pkbf(i2, i3);
            B1.w[2] = 0; B1.w[3] = 0;
        } else {
            B1.w[0] = B1.w[1] = B1.w[2] = B1.w[3] = 0;
        }

        f32x4 D0 = __builtin_amdgcn_mfma_f32_16x16x32_bf16(A1[0].v, B1.v, zero4, 0, 0, 0);
        f32x4 D1 = __builtin_amdgcn_mfma_f32_16x16x32_bf16(A1[1].v, B1.v, zero4, 0, 0, 0);
        {
            float h0 = fmaxf(D0[0] + b1v0.x, 0.f), h1 = fmaxf(D0[1] + b1v0.y, 0.f);
            float h2 = fmaxf(D0[2] + b1v0.z, 0.f), h3 = fmaxf(D0[3] + b1v0.w, 0.f);
            *reinterpret_cast<uint2*>(lds + c*80 + 8*g) = make_uint2(pkbf(h0, h1), pkbf(h2, h3));
            float k0 = fmaxf(D1[0] + b1v1.x, 0.f), k1 = fmaxf(D1[1] + b1v1.y, 0.f);
            float k2 = fmaxf(D1[2] + b1v1.z, 0.f), k3 = fmaxf(D1[3] + b1v1.w, 0.f);
            *reinterpret_cast<uint2*>(lds + c*80 + 32 + 8*g) = make_uint2(pkbf(k0, k1), pkbf(k2, k3));
        }
        frag_u B2;
        *reinterpret_cast<uint4*>(&B2.w[0]) = *reinterpret_cast<const uint4*>(lds + c*80 + 16*g);

        f32x4 E0 = __builtin_amdgcn_mfma_f32_16x16x32_bf16(A2[0].v, B2.v, zero4, 0, 0, 0);
        f32x4 E1 = __builtin_amdgcn_mfma_f32_16x16x32_bf16(A2[1].v, B2.v, zero4, 0, 0, 0);
        {
            float h0 = fmaxf(E0[0] + b2v0.x, 0.f), h1 = fmaxf(E0[1] + b2v0.y, 0.f);
            float h2 = fmaxf(E0[2] + b2v0.z, 0.f), h3 = fmaxf(E0[3] + b2v0.w, 0.f);
            *reinterpret_cast<uint2*>(lds + c*80 + 8*g) = make_uint2(pkbf(h0, h1), pkbf(h2, h3));
            float k0 = fmaxf(E1[0] + b2v1.x, 0.f), k1 = fmaxf(E1[1] + b2v1.y, 0.f);
            float k2 = fmaxf(E1[2] + b2v1.z, 0.f), k3 = fmaxf(E1[3] + b2v1.w, 0.f);
            *reinterpret_cast<uint2*>(lds + c*80 + 32 + 8*g) = make_uint2(pkbf(k0, k1), pkbf(k2, k3));
        }
        frag_u B3;
        *reinterpret_cast<uint4*>(&B3.w[0]) = *reinterpret_cast<const uint4*>(lds + c*80 + 16*g);

        f32x4 F = __builtin_amdgcn_mfma_f32_16x16x32_bf16(A3.v, B3.v, zero4, 0, 0, 0);
        if (lane < 16 && (pbase + c) < E) {
            uint2 o;
            o.x = pkh(F[0] + b30, F[1] + b31);
            o.y = pkh(F[2] + b32, F[3] + b33);
            vs[pbase + c] = o;
        }
    }
}

// ---------------- streaming segment reduces: 16 lanes per node ----------------
__global__ __launch_bounds__(256) void enc_reduce16_kernel(
    const u32* __restrict__ us, const int* __restrict__ off,
    float* __restrict__ h1, int N)
{
    int gt  = blockIdx.x * 256 + threadIdx.x;
    int i   = gt >> 4;
    int sub = gt & 15;
    if (i >= N) return;
    int beg = off[i], end = off[i + 1];
    float acc0 = 0.f, acc1 = 0.f;
    for (int p = beg + sub; p < end; p += 16) {
        float2 t = uph(us[p]);
        acc0 += t.x; acc1 += t.y;
    }
    #pragma unroll
    for (int o = 8; o >= 1; o >>= 1) {
        acc0 += __shfl_down(acc0, o, 16);
        acc1 += __shfl_down(acc1, o, 16);
    }
    if (sub == 0) {
        float inv = 1.0f / fmaxf((float)(end - beg), 1.0f);
        float2 o; o.x = acc0 * inv; o.y = acc1 * inv;
        reinterpret_cast<float2*>(h1)[i] = o;
    }
}

__global__ __launch_bounds__(256) void dec_reduce16_kernel(
    const uint2* __restrict__ vs, const int* __restrict__ off,
    float* __restrict__ out, int N)
{
    int gt  = blockIdx.x * 256 + threadIdx.x;
    int i   = gt >> 4;
    int sub = gt & 15;
    if (i >= N) return;
    int beg = off[i], end = off[i + 1];
    float acc0 = 0.f, acc1 = 0.f, acc2 = 0.f, acc3 = 0.f;
    for (int p = beg + sub; p < end; p += 16) {
        uint2 w = vs[p];
        float2 t0 = uph(w.x), t1 = uph(w.y);
        acc0 += t0.x; acc1 += t0.y; acc2 += t1.x; acc3 += t1.y;
    }
    #pragma unroll
    for (int o = 8; o >= 1; o >>= 1) {
        acc0 += __shfl_down(acc0, o, 16);
        acc1 += __shfl_down(acc1, o, 16);
        acc2 += __shfl_down(acc2, o, 16);
        acc3 += __shfl_down(acc3, o, 16);
    }
    if (sub == 0) {
        float inv = 1.0f / fmaxf((float)(end - beg), 1.0f);
        float4 o;
        o.x = acc0 * inv; o.y = acc1 * inv; o.z = acc2 * inv; o.w = acc3 * inv;
        reinterpret_cast<float4*>(out)[i] = o;
    }
}

// ---------------- Fallback (round-1 atomic path) ----------------
__global__ __launch_bounds__(256) void enc_edge_kernel(
    const float* __restrict__ x, const int* __restrict__ src, const int* __restrict__ dst,
    const float* __restrict__ ab,
    const float* __restrict__ W1, const float* __restrict__ b1,
    const float* __restrict__ W2, const float* __restrict__ b2,
    const float* __restrict__ W3, const float* __restrict__ b3,
    float* __restrict__ acc, float* __restrict__ cnt, int E)
{
    int e = blockIdx.x * blockDim.x + threadIdx.x;
    if (e >= E) return;
    int si = src[e];
    int di = dst[e];
    float4 xd = reinterpret_cast<const float4*>(x)[di];
    float4 xs = reinterpret_cast<const float4*>(x)[si];
    float a0 = ab[0], a1 = ab[1], a2 = ab[2], a3 = ab[3];
    float c0 = ab[4], c1 = ab[5], c2 = ab[6], c3 = ab[7];
    float in[2 * DD];
    in[0] = fmaf(xd.x, a0, c0); in[1] = fmaf(xd.y, a1, c1);
    in[2] = fmaf(xd.z, a2, c2); in[3] = fmaf(xd.w, a3, c3);
    in[4] = (xs.x - xd.x) * a0; in[5] = (xs.y - xd.y) * a1;
    in[6] = (xs.z - xd.z) * a2; in[7] = (xs.w - xd.w) * a3;
    float h[BIG];
    #pragma unroll
    for (int j = 0; j < BIG; ++j) {
        float t = b1[j];
        #pragma unroll
        for (int k = 0; k < 2 * DD; ++k) t = fmaf(in[k], W1[k * BIG + j], t);
        h[j] = fmaxf(t, 0.0f);
    }
    float g[BIG];
    #pragma unroll
    for (int j = 0; j < BIG; ++j) {
        float t = b2[j];
        #pragma unroll
        for (int k = 0; k < BIG; ++k) t = fmaf(h[k], W2[k * BIG + j], t);
        g[j] = fmaxf(t, 0.0f);
    }
    float u0 = b3[0], u1 = b3[1];
    #pragma unroll
    for (int k = 0; k < BIG; ++k) {
        u0 = fmaf(g[k], W3[k * HID + 0], u0);
        u1 = fmaf(g[k], W3[k * HID + 1], u1);
    }
    atomicAdd(&acc[di * HID + 0], fmaxf(u0, 0.0f));
    atomicAdd(&acc[di * HID + 1], fmaxf(u1, 0.0f));
    atomicAdd(&cnt[di], 1.0f);
}

__global__ void finalize_h1_kernel(float* __restrict__ acc, const float* __restrict__ cnt, int n)
{
    int i = blockIdx.x * blockDim.x + threadIdx.x;
    if (i >= n) return;
    float inv = 1.0f / fmaxf(cnt[i], 1.0f);
    acc[i * HID + 0] *= inv;
    acc[i * HID + 1] *= inv;
}

__global__ __launch_bounds__(256) void dec_edge_kernel(
    const float* __restrict__ h1, const int* __restrict__ src, const int* __restrict__ dst,
    const float* __restrict__ W1, const float* __restrict__ b1,
    const float* __restrict__ W2, const float* __restrict__ b2,
    const float* __restrict__ W3, const float* __restrict__ b3,
    float* __restrict__ out, int E)
{
    int e = blockIdx.x * blockDim.x + threadIdx.x;
    if (e >= E) return;
    int si = src[e];
    int di = dst[e];
    float2 hd = reinterpret_cast<const float2*>(h1)[di];
    float2 hs = reinterpret_cast<const float2*>(h1)[si];
    float in[2 * HID];
    in[0] = hd.x; in[1] = hd.y;
    in[2] = hs.x - hd.x; in[3] = hs.y - hd.y;
    float h[BIG];
    #pragma unroll
    for (int j = 0; j < BIG; ++j) {
        float t = b1[j];
        #pragma unroll
        for (int k = 0; k < 2 * HID; ++k) t = fmaf(in[k], W1[k * BIG + j], t);
        h[j] = fmaxf(t, 0.0f);
    }
    float g[BIG];
    #pragma unroll
    for (int j = 0; j < BIG; ++j) {
        float t = b2[j];
        #pragma unroll
        for (int k = 0; k < BIG; ++k) t = fmaf(h[k], W2[k * BIG + j], t);
        g[j] = fmaxf(t, 0.0f);
    }
    float u0 = b3[0], u1 = b3[1], u2 = b3[2], u3 = b3[3];
    #pragma unroll
    for (int k = 0; k < BIG; ++k) {
        u0 = fmaf(g[k], W3[k * DD + 0], u0);
        u1 = fmaf(g[k], W3[k * DD + 1], u1);
        u2 = fmaf(g[k], W3[k * DD + 2], u2);
        u3 = fmaf(g[k], W3[k * DD + 3], u3);
    }
    atomicAdd(&out[di * DD + 0], u0);
    atomicAdd(&out[di * DD + 1], u1);
    atomicAdd(&out[di * DD + 2], u2);
    atomicAdd(&out[di * DD + 3], u3);
}

__global__ void finalize_out_kernel(float* __restrict__ out, const float* __restrict__ cnt, int n)
{
    int i = blockIdx.x * blockDim.x + threadIdx.x;
    if (i >= n) return;
    float inv = 1.0f / fmaxf(cnt[i], 1.0f);
    float4 v = reinterpret_cast<float4*>(out)[i];
    v.x *= inv; v.y *= inv; v.z *= inv; v.w *= inv;
    reinterpret_cast<float4*>(out)[i] = v;
}

// ---------------- launch ----------------
extern "C" void kernel_launch(void* const* d_in, const int* in_sizes, int n_in,
                              void* d_out, int out_size, void* d_ws, size_t ws_size,
                              hipStream_t stream)
{
    const float* x     = (const float*)d_in[0];
    const int*   src   = (const int*)  d_in[1];
    const int*   dst   = (const int*)  d_in[2];
    const float* gamma = (const float*)d_in[3];
    const float* beta  = (const float*)d_in[4];
    const float* eW1 = (const float*)d_in[5];  const float* eb1 = (const float*)d_in[6];
    const float* eW2 = (const float*)d_in[7];  const float* eb2 = (const float*)d_in[8];
    const float* eW3 = (const float*)d_in[9];  const float* eb3 = (const float*)d_in[10];
    const float* dW1 = (const float*)d_in[11]; const float* db1 = (const float*)d_in[12];
    const float* dW2 = (const float*)d_in[13]; const float* db2 = (const float*)d_in[14];
    const float* dW3 = (const float*)d_in[15]; const float* db3 = (const float*)d_in[16];

    const int N = in_sizes[0] / DD;
    const int E = in_sizes[1];
    float* out = (float*)d_out;

    // Workspace (~65.6 MB at N=100k, E=3.2M — same as proven rounds 4/6).
    // Region A (E*8 bytes) is time-multiplexed: {rank E*2, u E*4} until
    // scatter_csr completes, then vs (E*8) from dec_mfma on.
    auto rnd16 = [](size_t b) { return (b + 15) & ~(size_t)15; };
    size_t need = 0;
    size_t o_sums  = need; need += rnd16(8 * 4);
    size_t o_ab    = need; need += rnd16(8 * 4);
    size_t o_bsum  = need; need += rnd16(256 * 4);
    size_t o_bbase = need; need += rnd16(256 * 4);
    size_t o_deg   = need; need += rnd16((size_t)N * 4);
    size_t o_off   = need; need += rnd16((size_t)(N + 1) * 4);
    size_t o_h1    = need; need += rnd16((size_t)2 * N * 4);
    size_t o_us    = need; need += rnd16((size_t)E * 4);   // half2 per slot
    size_t o_sd    = need; need += rnd16((size_t)E * 8);   // int2 per slot
    size_t o_A     = need; need += rnd16((size_t)E * 8);   // rank(E*2)+u(E*4) -> vs(E*8)

    char* wsb = (char*)d_ws;

    if (ws_size >= need && N > 0 && E > 0) {
        float*          sums  = (float*)(wsb + o_sums);
        float*          ab    = (float*)(wsb + o_ab);
        int*            bsum  = (int*)  (wsb + o_bsum);
        int*            bbase = (int*)  (wsb + o_bbase);
        int*            deg   = (int*)  (wsb + o_deg);
        int*            off   = (int*)  (wsb + o_off);
        float*          h1    = (float*)(wsb + o_h1);
        u32*            us    = (u32*)  (wsb + o_us);
        int2*           sd    = (int2*) (wsb + o_sd);
        unsigned short* rank  = (unsigned short*)(wsb + o_A);
        u32*            u     = (u32*)  (wsb + o_A + rnd16((size_t)E * 2));
        uint2*          vs    = (uint2*)(wsb + o_A);

        hipMemsetAsync(sums, 0, 8 * sizeof(float), stream);
        hipMemsetAsync(deg, 0, (size_t)N * sizeof(int), stream);

        bn_reduce_kernel<<<256, 256, 0, stream>>>(x, N, sums);
        bn_finalize_kernel<<<1, 64, 0, stream>>>(sums, gamma, beta, ab, 1.0f / (float)N);

        int eblocks = (E + 255) / 256;
        int nbatch = (E + 15) / 16;
        int mblocks = 2048;                 // was 1024: occupancy was grid-limited (43%)
        int nwaves = mblocks * 4;

        // fused: MLP (MFMA) + rank histogram + u (half2) store
        enc_mfma_rank_kernel<<<mblocks, 256, 0, stream>>>(x, src, dst, ab,
                                                          eW1, eb1, eW2, eb2, eW3, eb3,
                                                          u, deg, rank, N, E, nbatch, nwaves);

        int nb = (N + SCAN_CHUNK - 1) / SCAN_CHUNK;
        scan_block_sums_kernel<<<nb, 256, 0, stream>>>(deg, N, bsum);
        scan_base_kernel<<<1, 64, 0, stream>>>(bsum, nb, bbase);
        scan_write_kernel<<<nb, 256, 0, stream>>>(deg, N, bbase, off);

        // place payloads in CSR order; after this rank & u are dead (region A -> vs)
        scatter_csr_kernel<<<eblocks, 256, 0, stream>>>(src, dst, rank, off, u, sd, us, E);

        int rblocks = ((N * 16) + 255) / 256;
        enc_reduce16_kernel<<<rblocks, 256, 0, stream>>>(us, off, h1, N);

        dec_mfma_kernel<<<mblocks, 256, 0, stream>>>(h1, sd,
                                                     dW1, db1, dW2, db2, dW3, db3,
                                                     vs, N, E, nbatch, nwaves);
        dec_reduce16_kernel<<<rblocks, 256, 0, stream>>>(vs, off, out, N);
    } else {
        float* ws   = (float*)d_ws;
        float* sums = ws;
        float* ab   = ws + 8;
        float* cnt  = ws + 16;
        float* acc1 = ws + 16 + N;

        hipMemsetAsync(sums, 0, 16 * sizeof(float), stream);
        hipMemsetAsync(cnt, 0, (size_t)(3 * N) * sizeof(float), stream);
        hipMemsetAsync(out, 0, (size_t)out_size * sizeof(float), stream);

        bn_reduce_kernel<<<256, 256, 0, stream>>>(x, N, sums);
        bn_finalize_kernel<<<1, 64, 0, stream>>>(sums, gamma, beta, ab, 1.0f / (float)N);

        int eblocks = (E + 255) / 256;
        enc_edge_kernel<<<eblocks, 256, 0, stream>>>(x, src, dst, ab,
                                                     eW1, eb1, eW2, eb2, eW3, eb3,
                                                     acc1, cnt, E);
        finalize_h1_kernel<<<(N + 255) / 256, 256, 0, stream>>>(acc1, cnt, N);
        dec_edge_kernel<<<eblocks, 256, 0, stream>>>(acc1, src, dst,
                                                     dW1, db1, dW2, db2, dW3, db3,
                                                     out, E);
        finalize_out_kernel<<<(N + 255) / 256, 256, 0, stream>>>(out, cnt, N);
    }
}

// Round 8
// 281.204 us; speedup vs baseline: 14.3389x; 1.2343x over previous
//
#include <hip/hip_runtime.h>
#include <hip/hip_bf16.h>
#include <hip/hip_fp16.h>
#include <math.h>

// EdgeNetEMD: BatchNorm(4) -> EdgeConv(8->32->32->2, relu_last) -> EdgeConv(4->32->32->4)
// N=100000 nodes, E=3200000 edges, fp32 in/out.
// Round 8: enc grid back to 1024 blocks (atomic pass degrades with more waves:
// 129@hist-only, 143@1024, 173@2048 -- fabric contention). dec at 2048 (no
// atomics, TLP helps). Scatter packs {src,u} into ONE uint2 write; dst-per-slot
// is written coalesced by enc_reduce (dsts[p]=i). dec reads srcu+dsts coalesced.

constexpr int DD  = 4;
constexpr int BIG = 32;
constexpr int HID = 2;

typedef __attribute__((ext_vector_type(8))) short bf16x8;
typedef __attribute__((ext_vector_type(4))) float f32x4;
typedef unsigned int u32;

union frag_u { bf16x8 v; u32 w[4]; };

__device__ inline unsigned short bfbits(float f) {
    __hip_bfloat16 h = __float2bfloat16(f);
    unsigned short s; __builtin_memcpy(&s, &h, 2); return s;
}
__device__ inline u32 pkbf(float lo, float hi) {
    return (u32)bfbits(lo) | ((u32)bfbits(hi) << 16);
}
__device__ inline u32 pkh(float lo, float hi) {
    __half2 h = __floats2half2_rn(lo, hi);
    u32 w; __builtin_memcpy(&w, &h, 4); return w;
}
__device__ inline float2 uph(u32 w) {
    __half2 h; __builtin_memcpy(&h, &w, 4);
    return __half22float2(h);
}

// ---------------- BatchNorm statistics ----------------
__global__ void bn_reduce_kernel(const float* __restrict__ x, int n,
                                 float* __restrict__ sums)
{
    float s0=0.f,s1=0.f,s2=0.f,s3=0.f,q0=0.f,q1=0.f,q2=0.f,q3=0.f;
    int stride = gridDim.x * blockDim.x;
    for (int i = blockIdx.x * blockDim.x + threadIdx.x; i < n; i += stride) {
        float4 v = reinterpret_cast<const float4*>(x)[i];
        s0 += v.x; s1 += v.y; s2 += v.z; s3 += v.w;
        q0 = fmaf(v.x, v.x, q0); q1 = fmaf(v.y, v.y, q1);
        q2 = fmaf(v.z, v.z, q2); q3 = fmaf(v.w, v.w, q3);
    }
    #pragma unroll
    for (int off = 32; off >= 1; off >>= 1) {
        s0 += __shfl_down(s0, off); s1 += __shfl_down(s1, off);
        s2 += __shfl_down(s2, off); s3 += __shfl_down(s3, off);
        q0 += __shfl_down(q0, off); q1 += __shfl_down(q1, off);
        q2 += __shfl_down(q2, off); q3 += __shfl_down(q3, off);
    }
    __shared__ float red[4][8];
    int wave = threadIdx.x >> 6;
    int lane = threadIdx.x & 63;
    if (lane == 0) {
        red[wave][0]=s0; red[wave][1]=s1; red[wave][2]=s2; red[wave][3]=s3;
        red[wave][4]=q0; red[wave][5]=q1; red[wave][6]=q2; red[wave][7]=q3;
    }
    __syncthreads();
    if (threadIdx.x < 8) {
        int nw = blockDim.x >> 6;
        float t = 0.f;
        for (int w = 0; w < nw; ++w) t += red[w][threadIdx.x];
        atomicAdd(&sums[threadIdx.x], t);
    }
}

__global__ void bn_finalize_kernel(const float* __restrict__ sums,
                                   const float* __restrict__ gamma,
                                   const float* __restrict__ beta,
                                   float* __restrict__ ab, float invN)
{
    int f = threadIdx.x;
    if (f < DD) {
        float mean = sums[f] * invN;
        float var  = sums[DD + f] * invN - mean * mean;
        float a = gamma[f] / sqrtf(var + 1e-5f);
        ab[f]      = a;
        ab[DD + f] = beta[f] - mean * a;
    }
}

// ---------------- scan (off = exclusive prefix of deg) ----------------
constexpr int SCAN_CHUNK = 1024;

__global__ __launch_bounds__(256) void scan_block_sums_kernel(const int* __restrict__ deg, int n,
                                                              int* __restrict__ bsum)
{
    int b = blockIdx.x;
    int base = b * SCAN_CHUNK + threadIdx.x * 4;
    int s = 0;
    #pragma unroll
    for (int k = 0; k < 4; ++k) { int i = base + k; if (i < n) s += deg[i]; }
    #pragma unroll
    for (int o = 32; o >= 1; o >>= 1) s += __shfl_down(s, o);
    __shared__ int red[4];
    int wave = threadIdx.x >> 6, lane = threadIdx.x & 63;
    if (lane == 0) red[wave] = s;
    __syncthreads();
    if (threadIdx.x == 0) bsum[b] = red[0] + red[1] + red[2] + red[3];
}

// bsum and bbase MUST be separate buffers (round-2 aliasing fault).
__global__ void scan_base_kernel(const int* bsum, int nb, int* bbase)
{
    if (threadIdx.x == 0) {
        int running = 0;
        for (int b = 0; b < nb; ++b) {
            int v = bsum[b];
            bbase[b] = running;
            running += v;
        }
    }
}

__global__ __launch_bounds__(256) void scan_write_kernel(const int* __restrict__ deg, int n,
                                                         const int* __restrict__ bbase,
                                                         int* __restrict__ off)
{
    int b = blockIdx.x, tid = threadIdx.x;
    int base = b * SCAN_CHUNK + tid * 4;
    int v[4]; int s = 0;
    #pragma unroll
    for (int k = 0; k < 4; ++k) { int i = base + k; v[k] = (i < n) ? deg[i] : 0; s += v[k]; }
    int lane = tid & 63, wave = tid >> 6;
    int inc = s;
    #pragma unroll
    for (int o = 1; o < 64; o <<= 1) { int t = __shfl_up(inc, o); if (lane >= o) inc += t; }
    __shared__ int wsum[4];
    if (lane == 63) wsum[wave] = inc;
    __syncthreads();
    int wbase = 0;
    for (int w = 0; w < wave; ++w) wbase += wsum[w];
    int cur = bbase[b] + wbase + inc - s;
    #pragma unroll
    for (int k = 0; k < 4; ++k) {
        int i = base + k;
        if (i < n) {
            off[i] = cur;
            cur += v[k];
            if (i == n - 1) off[n] = cur;
        }
    }
}

// ---------------- scatter {src, u} into CSR order (single 8B write/edge) ----------------
__global__ __launch_bounds__(256) void scatter_srcu_kernel(const int* __restrict__ src,
                                                           const int* __restrict__ dst,
                                                           const unsigned short* __restrict__ rank,
                                                           const int* __restrict__ off,
                                                           const u32* __restrict__ u,
                                                           uint2* __restrict__ srcu, int E)
{
    int e = blockIdx.x * 256 + threadIdx.x;
    if (e >= E) return;
    int d = dst[e];
    int idx = off[d] + (int)rank[e];
    idx = min(max(idx, 0), E - 1);   // safety clamp (wrong value beats a fault)
    srcu[idx] = make_uint2((u32)src[e], u[e]);
}

// ---------------- Encoder per-edge MLP via MFMA + fused rank histogram ----------------
// Per wave, per batch of 16 edges: In^T [K x 16edges], H^T = W^T * In^T.
// k-mapping for A/B fragments: k = 8*(lane>>4) + i (self-consistent A/B).
// C/D layout (HW-verified m89): col = lane&15 (edge), row = 4*(lane>>4)+reg (feat).
// Fused: lanes 0-15 (which load dst[e] anyway) do atomicAdd(deg)+rank store.
// Grid: 1024 blocks. DO NOT raise: atomic pass slows with more waves
// (129us hist-only, 143us @1024, 173us @2048 -- fabric contention).
__global__ __launch_bounds__(256) void enc_mfma_rank_kernel(
    const float* __restrict__ x, const int* __restrict__ src, const int* __restrict__ dst,
    const float* __restrict__ ab,
    const float* __restrict__ W1, const float* __restrict__ b1,
    const float* __restrict__ W2, const float* __restrict__ b2,
    const float* __restrict__ W3, const float* __restrict__ b3,
    u32* __restrict__ u /* half2 per edge */,
    int* __restrict__ deg, unsigned short* __restrict__ rank,
    int N, int E, int nbatch, int nwaves)
{
    __shared__ __align__(16) char lds_all[4][16 * 80];
    const int tid  = threadIdx.x;
    const int wid  = tid >> 6;
    const int lane = tid & 63;
    const int c    = lane & 15;
    const int g    = lane >> 4;
    char* lds = lds_all[wid];

    // ---- weight fragments (once per kernel) ----
    frag_u A1[2];
    #pragma unroll
    for (int t = 0; t < 2; ++t) {
        A1[t].w[0] = A1[t].w[1] = A1[t].w[2] = A1[t].w[3] = 0;
        if (g == 0) {
            int of = 16 * t + c;
            #pragma unroll
            for (int j = 0; j < 4; ++j)
                A1[t].w[j] = pkbf(W1[(2*j+0)*BIG + of], W1[(2*j+1)*BIG + of]);
        }
    }
    frag_u A2[2];
    #pragma unroll
    for (int t = 0; t < 2; ++t) {
        int of = 16 * t + c;
        #pragma unroll
        for (int j = 0; j < 4; ++j)
            A2[t].w[j] = pkbf(W2[(8*g + 2*j + 0)*BIG + of], W2[(8*g + 2*j + 1)*BIG + of]);
    }
    frag_u A3;
    A3.w[0] = A3.w[1] = A3.w[2] = A3.w[3] = 0;
    if (c < HID) {
        #pragma unroll
        for (int j = 0; j < 4; ++j)
            A3.w[j] = pkbf(W3[(8*g + 2*j + 0)*HID + c], W3[(8*g + 2*j + 1)*HID + c]);
    }
    float4 b1v0 = *reinterpret_cast<const float4*>(b1 + 4*g);
    float4 b1v1 = *reinterpret_cast<const float4*>(b1 + 16 + 4*g);
    float4 b2v0 = *reinterpret_cast<const float4*>(b2 + 4*g);
    float4 b2v1 = *reinterpret_cast<const float4*>(b2 + 16 + 4*g);
    float b30 = b3[0], b31 = b3[1];
    float a0 = ab[0], a1 = ab[1], a2 = ab[2], a3 = ab[3];
    float c0 = ab[4], c1 = ab[5], c2 = ab[6], c3 = ab[7];

    const f32x4 zero4 = {0.f, 0.f, 0.f, 0.f};

    for (int batch = blockIdx.x * 4 + wid; batch < nbatch; batch += nwaves) {
        int ebase = batch * 16;
        int e = min(ebase + c, E - 1);
        bool live = (ebase + c) < E;

        float4 xv = make_float4(0.f, 0.f, 0.f, 0.f);
        if (lane < 32) {
            const int* ip = (lane < 16) ? dst : src;
            int idx = ip[e];
            // fused rank histogram: lanes 0-15 hold dst[e]
            if (lane < 16 && live) {
                int dcl = min(max(idx, 0), N - 1);
                int old = atomicAdd(&deg[dcl], 1);
                rank[e] = (unsigned short)old;
            }
            idx = min(max(idx, 0), N - 1);
            xv = reinterpret_cast<const float4*>(x)[idx];
        }
        float xd0 = __shfl(xv.x, c),      xd1 = __shfl(xv.y, c);
        float xd2 = __shfl(xv.z, c),      xd3 = __shfl(xv.w, c);
        float xs0 = __shfl(xv.x, 16 + c), xs1 = __shfl(xv.y, 16 + c);
        float xs2 = __shfl(xv.z, 16 + c), xs3 = __shfl(xv.w, 16 + c);

        float n0 = fmaf(xd0, a0, c0), n1 = fmaf(xd1, a1, c1);
        float n2 = fmaf(xd2, a2, c2), n3 = fmaf(xd3, a3, c3);
        float d0 = (xs0 - xd0) * a0,  d1 = (xs1 - xd1) * a1;
        float d2 = (xs2 - xd2) * a2,  d3 = (xs3 - xd3) * a3;

        frag_u B1;
        if (g == 0) {
            B1.w[0] = pkbf(n0, n1); B1.w[1] = pkbf(n2, n3);
            B1.w[2] = pkbf(d0, d1); B1.w[3] = pkbf(d2, d3);
        } else {
            B1.w[0] = B1.w[1] = B1.w[2] = B1.w[3] = 0;
        }

        // ---- layer 1 ----
        f32x4 D0 = __builtin_amdgcn_mfma_f32_16x16x32_bf16(A1[0].v, B1.v, zero4, 0, 0, 0);
        f32x4 D1 = __builtin_amdgcn_mfma_f32_16x16x32_bf16(A1[1].v, B1.v, zero4, 0, 0, 0);
        {
            float h0 = fmaxf(D0[0] + b1v0.x, 0.f), h1 = fmaxf(D0[1] + b1v0.y, 0.f);
            float h2 = fmaxf(D0[2] + b1v0.z, 0.f), h3 = fmaxf(D0[3] + b1v0.w, 0.f);
            *reinterpret_cast<uint2*>(lds + c*80 + 8*g) = make_uint2(pkbf(h0, h1), pkbf(h2, h3));
            float k0 = fmaxf(D1[0] + b1v1.x, 0.f), k1 = fmaxf(D1[1] + b1v1.y, 0.f);
            float k2 = fmaxf(D1[2] + b1v1.z, 0.f), k3 = fmaxf(D1[3] + b1v1.w, 0.f);
            *reinterpret_cast<uint2*>(lds + c*80 + 32 + 8*g) = make_uint2(pkbf(k0, k1), pkbf(k2, k3));
        }
        frag_u B2;
        *reinterpret_cast<uint4*>(&B2.w[0]) = *reinterpret_cast<const uint4*>(lds + c*80 + 16*g);

        // ---- layer 2 ----
        f32x4 E0 = __builtin_amdgcn_mfma_f32_16x16x32_bf16(A2[0].v, B2.v, zero4, 0, 0, 0);
        f32x4 E1 = __builtin_amdgcn_mfma_f32_16x16x32_bf16(A2[1].v, B2.v, zero4, 0, 0, 0);
        {
            float h0 = fmaxf(E0[0] + b2v0.x, 0.f), h1 = fmaxf(E0[1] + b2v0.y, 0.f);
            float h2 = fmaxf(E0[2] + b2v0.z, 0.f), h3 = fmaxf(E0[3] + b2v0.w, 0.f);
            *reinterpret_cast<uint2*>(lds + c*80 + 8*g) = make_uint2(pkbf(h0, h1), pkbf(h2, h3));
            float k0 = fmaxf(E1[0] + b2v1.x, 0.f), k1 = fmaxf(E1[1] + b2v1.y, 0.f);
            float k2 = fmaxf(E1[2] + b2v1.z, 0.f), k3 = fmaxf(E1[3] + b2v1.w, 0.f);
            *reinterpret_cast<uint2*>(lds + c*80 + 32 + 8*g) = make_uint2(pkbf(k0, k1), pkbf(k2, k3));
        }
        frag_u B3;
        *reinterpret_cast<uint4*>(&B3.w[0]) = *reinterpret_cast<const uint4*>(lds + c*80 + 16*g);

        // ---- layer 3 ----
        f32x4 F = __builtin_amdgcn_mfma_f32_16x16x32_bf16(A3.v, B3.v, zero4, 0, 0, 0);
        if (lane < 16 && live) {
            float o0 = fmaxf(F[0] + b30, 0.f);
            float o1 = fmaxf(F[1] + b31, 0.f);
            u[ebase + c] = pkh(o0, o1);
        }
    }
}

// ---------------- Decoder per-edge MLP via MFMA, CSR slot order ----------------
// Slot p: srcu[p].x = src, dsts[p] = dst (written coalesced by enc_reduce);
// in = [h1[dst], h1[src]-h1[dst]]; vs[p] = out (half4).
__global__ __launch_bounds__(256) void dec_mfma_kernel(
    const float* __restrict__ h1n, const uint2* __restrict__ srcu,
    const int* __restrict__ dsts,
    const float* __restrict__ W1, const float* __restrict__ b1,
    const float* __restrict__ W2, const float* __restrict__ b2,
    const float* __restrict__ W3, const float* __restrict__ b3,
    uint2* __restrict__ vs /* half4 per slot */, int N, int E, int nbatch, int nwaves)
{
    __shared__ __align__(16) char lds_all[4][16 * 80];
    const int tid  = threadIdx.x;
    const int wid  = tid >> 6;
    const int lane = tid & 63;
    const int c    = lane & 15;
    const int g    = lane >> 4;
    char* lds = lds_all[wid];

    frag_u A1[2];
    #pragma unroll
    for (int t = 0; t < 2; ++t) {
        A1[t].w[0] = A1[t].w[1] = A1[t].w[2] = A1[t].w[3] = 0;
        if (g == 0) {
            int of = 16 * t + c;
            A1[t].w[0] = pkbf(W1[0*BIG + of], W1[1*BIG + of]);
            A1[t].w[1] = pkbf(W1[2*BIG + of], W1[3*BIG + of]);
        }
    }
    frag_u A2[2];
    #pragma unroll
    for (int t = 0; t < 2; ++t) {
        int of = 16 * t + c;
        #pragma unroll
        for (int j = 0; j < 4; ++j)
            A2[t].w[j] = pkbf(W2[(8*g + 2*j + 0)*BIG + of], W2[(8*g + 2*j + 1)*BIG + of]);
    }
    frag_u A3;
    A3.w[0] = A3.w[1] = A3.w[2] = A3.w[3] = 0;
    if (c < DD) {
        #pragma unroll
        for (int j = 0; j < 4; ++j)
            A3.w[j] = pkbf(W3[(8*g + 2*j + 0)*DD + c], W3[(8*g + 2*j + 1)*DD + c]);
    }
    float4 b1v0 = *reinterpret_cast<const float4*>(b1 + 4*g);
    float4 b1v1 = *reinterpret_cast<const float4*>(b1 + 16 + 4*g);
    float4 b2v0 = *reinterpret_cast<const float4*>(b2 + 4*g);
    float4 b2v1 = *reinterpret_cast<const float4*>(b2 + 16 + 4*g);
    float b30 = b3[0], b31 = b3[1], b32 = b3[2], b33 = b3[3];

    const f32x4 zero4 = {0.f, 0.f, 0.f, 0.f};

    for (int batch = blockIdx.x * 4 + wid; batch < nbatch; batch += nwaves) {
        int pbase = batch * 16;
        int p = min(pbase + c, E - 1);

        int sv_ = 0, dv_ = 0;
        if (lane < 16) {
            sv_ = (int)srcu[p].x;
            dv_ = dsts[p];
        }
        int sv = __shfl(sv_, c);
        int dv = __shfl(dv_, c);

        float2 hv = make_float2(0.f, 0.f);
        if (lane < 32) {
            int idx = (lane < 16) ? dv : sv;
            idx = min(max(idx, 0), N - 1);
            hv = reinterpret_cast<const float2*>(h1n)[idx];
        }
        float hd0 = __shfl(hv.x, c),      hd1 = __shfl(hv.y, c);
        float hs0 = __shfl(hv.x, 16 + c), hs1 = __shfl(hv.y, 16 + c);
        float i0 = hd0, i1 = hd1, i2 = hs0 - hd0, i3 = hs1 - hd1;

        frag_u B1;
        if (g == 0) {
            B1.w[0] = pkbf(i0, i1); B1.w[1] = pkbf(i2, i3);
            B1.w[2] = 0; B1.w[3] = 0;
        } else {
            B1.w[0] = B1.w[1] = B1.w[2] = B1.w[3] = 0;
        }

        f32x4 D0 = __builtin_amdgcn_mfma_f32_16x16x32_bf16(A1[0].v, B1.v, zero4, 0, 0, 0);
        f32x4 D1 = __builtin_amdgcn_mfma_f32_16x16x32_bf16(A1[1].v, B1.v, zero4, 0, 0, 0);
        {
            float h0 = fmaxf(D0[0] + b1v0.x, 0.f), h1 = fmaxf(D0[1] + b1v0.y, 0.f);
            float h2 = fmaxf(D0[2] + b1v0.z, 0.f), h3 = fmaxf(D0[3] + b1v0.w, 0.f);
            *reinterpret_cast<uint2*>(lds + c*80 + 8*g) = make_uint2(pkbf(h0, h1), pkbf(h2, h3));
            float k0 = fmaxf(D1[0] + b1v1.x, 0.f), k1 = fmaxf(D1[1] + b1v1.y, 0.f);
            float k2 = fmaxf(D1[2] + b1v1.z, 0.f), k3 = fmaxf(D1[3] + b1v1.w, 0.f);
            *reinterpret_cast<uint2*>(lds + c*80 + 32 + 8*g) = make_uint2(pkbf(k0, k1), pkbf(k2, k3));
        }
        frag_u B2;
        *reinterpret_cast<uint4*>(&B2.w[0]) = *reinterpret_cast<const uint4*>(lds + c*80 + 16*g);

        f32x4 E0 = __builtin_amdgcn_mfma_f32_16x16x32_bf16(A2[0].v, B2.v, zero4, 0, 0, 0);
        f32x4 E1 = __builtin_amdgcn_mfma_f32_16x16x32_bf16(A2[1].v, B2.v, zero4, 0, 0, 0);
        {
            float h0 = fmaxf(E0[0] + b2v0.x, 0.f), h1 = fmaxf(E0[1] + b2v0.y, 0.f);
            float h2 = fmaxf(E0[2] + b2v0.z, 0.f), h3 = fmaxf(E0[3] + b2v0.w, 0.f);
            *reinterpret_cast<uint2*>(lds + c*80 + 8*g) = make_uint2(pkbf(h0, h1), pkbf(h2, h3));
            float k0 = fmaxf(E1[0] + b2v1.x, 0.f), k1 = fmaxf(E1[1] + b2v1.y, 0.f);
            float k2 = fmaxf(E1[2] + b2v1.z, 0.f), k3 = fmaxf(E1[3] + b2v1.w, 0.f);
            *reinterpret_cast<uint2*>(lds + c*80 + 32 + 8*g) = make_uint2(pkbf(k0, k1), pkbf(k2, k3));
        }
        frag_u B3;
        *reinterpret_cast<uint4*>(&B3.w[0]) = *reinterpret_cast<const uint4*>(lds + c*80 + 16*g);

        f32x4 F = __builtin_amdgcn_mfma_f32_16x16x32_bf16(A3.v, B3.v, zero4, 0, 0, 0);
        if (lane < 16 && (pbase + c) < E) {
            uint2 o;
            o.x = pkh(F[0] + b30, F[1] + b31);
            o.y = pkh(F[2] + b32, F[3] + b33);
            vs[pbase + c] = o;
        }
    }
}

// ---------------- streaming segment reduces: 16 lanes per node ----------------
// enc_reduce also writes dsts[p] = i (coalesced) for dec's slot->dst lookup.
__global__ __launch_bounds__(256) void enc_reduce16_kernel(
    const uint2* __restrict__ srcu, const int* __restrict__ off,
    float* __restrict__ h1, int* __restrict__ dsts, int N)
{
    int gt  = blockIdx.x * 256 + threadIdx.x;
    int i   = gt >> 4;
    int sub = gt & 15;
    if (i >= N) return;
    int beg = off[i], end = off[i + 1];
    float acc0 = 0.f, acc1 = 0.f;
    for (int p = beg + sub; p < end; p += 16) {
        float2 t = uph(srcu[p].y);
        acc0 += t.x; acc1 += t.y;
        dsts[p] = i;
    }
    #pragma unroll
    for (int o = 8; o >= 1; o >>= 1) {
        acc0 += __shfl_down(acc0, o, 16);
        acc1 += __shfl_down(acc1, o, 16);
    }
    if (sub == 0) {
        float inv = 1.0f / fmaxf((float)(end - beg), 1.0f);
        float2 o; o.x = acc0 * inv; o.y = acc1 * inv;
        reinterpret_cast<float2*>(h1)[i] = o;
    }
}

__global__ __launch_bounds__(256) void dec_reduce16_kernel(
    const uint2* __restrict__ vs, const int* __restrict__ off,
    float* __restrict__ out, int N)
{
    int gt  = blockIdx.x * 256 + threadIdx.x;
    int i   = gt >> 4;
    int sub = gt & 15;
    if (i >= N) return;
    int beg = off[i], end = off[i + 1];
    float acc0 = 0.f, acc1 = 0.f, acc2 = 0.f, acc3 = 0.f;
    for (int p = beg + sub; p < end; p += 16) {
        uint2 w = vs[p];
        float2 t0 = uph(w.x), t1 = uph(w.y);
        acc0 += t0.x; acc1 += t0.y; acc2 += t1.x; acc3 += t1.y;
    }
    #pragma unroll
    for (int o = 8; o >= 1; o >>= 1) {
        acc0 += __shfl_down(acc0, o, 16);
        acc1 += __shfl_down(acc1, o, 16);
        acc2 += __shfl_down(acc2, o, 16);
        acc3 += __shfl_down(acc3, o, 16);
    }
    if (sub == 0) {
        float inv = 1.0f / fmaxf((float)(end - beg), 1.0f);
        float4 o;
        o.x = acc0 * inv; o.y = acc1 * inv; o.z = acc2 * inv; o.w = acc3 * inv;
        reinterpret_cast<float4*>(out)[i] = o;
    }
}

// ---------------- Fallback (round-1 atomic path) ----------------
__global__ __launch_bounds__(256) void enc_edge_kernel(
    const float* __restrict__ x, const int* __restrict__ src, const int* __restrict__ dst,
    const float* __restrict__ ab,
    const float* __restrict__ W1, const float* __restrict__ b1,
    const float* __restrict__ W2, const float* __restrict__ b2,
    const float* __restrict__ W3, const float* __restrict__ b3,
    float* __restrict__ acc, float* __restrict__ cnt, int E)
{
    int e = blockIdx.x * blockDim.x + threadIdx.x;
    if (e >= E) return;
    int si = src[e];
    int di = dst[e];
    float4 xd = reinterpret_cast<const float4*>(x)[di];
    float4 xs = reinterpret_cast<const float4*>(x)[si];
    float a0 = ab[0], a1 = ab[1], a2 = ab[2], a3 = ab[3];
    float c0 = ab[4], c1 = ab[5], c2 = ab[6], c3 = ab[7];
    float in[2 * DD];
    in[0] = fmaf(xd.x, a0, c0); in[1] = fmaf(xd.y, a1, c1);
    in[2] = fmaf(xd.z, a2, c2); in[3] = fmaf(xd.w, a3, c3);
    in[4] = (xs.x - xd.x) * a0; in[5] = (xs.y - xd.y) * a1;
    in[6] = (xs.z - xd.z) * a2; in[7] = (xs.w - xd.w) * a3;
    float h[BIG];
    #pragma unroll
    for (int j = 0; j < BIG; ++j) {
        float t = b1[j];
        #pragma unroll
        for (int k = 0; k < 2 * DD; ++k) t = fmaf(in[k], W1[k * BIG + j], t);
        h[j] = fmaxf(t, 0.0f);
    }
    float g[BIG];
    #pragma unroll
    for (int j = 0; j < BIG; ++j) {
        float t = b2[j];
        #pragma unroll
        for (int k = 0; k < BIG; ++k) t = fmaf(h[k], W2[k * BIG + j], t);
        g[j] = fmaxf(t, 0.0f);
    }
    float u0 = b3[0], u1 = b3[1];
    #pragma unroll
    for (int k = 0; k < BIG; ++k) {
        u0 = fmaf(g[k], W3[k * HID + 0], u0);
        u1 = fmaf(g[k], W3[k * HID + 1], u1);
    }
    atomicAdd(&acc[di * HID + 0], fmaxf(u0, 0.0f));
    atomicAdd(&acc[di * HID + 1], fmaxf(u1, 0.0f));
    atomicAdd(&cnt[di], 1.0f);
}

__global__ void finalize_h1_kernel(float* __restrict__ acc, const float* __restrict__ cnt, int n)
{
    int i = blockIdx.x * blockDim.x + threadIdx.x;
    if (i >= n) return;
    float inv = 1.0f / fmaxf(cnt[i], 1.0f);
    acc[i * HID + 0] *= inv;
    acc[i * HID + 1] *= inv;
}

__global__ __launch_bounds__(256) void dec_edge_kernel(
    const float* __restrict__ h1, const int* __restrict__ src, const int* __restrict__ dst,
    const float* __restrict__ W1, const float* __restrict__ b1,
    const float* __restrict__ W2, const float* __restrict__ b2,
    const float* __restrict__ W3, const float* __restrict__ b3,
    float* __restrict__ out, int E)
{
    int e = blockIdx.x * blockDim.x + threadIdx.x;
    if (e >= E) return;
    int si = src[e];
    int di = dst[e];
    float2 hd = reinterpret_cast<const float2*>(h1)[di];
    float2 hs = reinterpret_cast<const float2*>(h1)[si];
    float in[2 * HID];
    in[0] = hd.x; in[1] = hd.y;
    in[2] = hs.x - hd.x; in[3] = hs.y - hd.y;
    float h[BIG];
    #pragma unroll
    for (int j = 0; j < BIG; ++j) {
        float t = b1[j];
        #pragma unroll
        for (int k = 0; k < 2 * HID; ++k) t = fmaf(in[k], W1[k * BIG + j], t);
        h[j] = fmaxf(t, 0.0f);
    }
    float g[BIG];
    #pragma unroll
    for (int j = 0; j < BIG; ++j) {
        float t = b2[j];
        #pragma unroll
        for (int k = 0; k < BIG; ++k) t = fmaf(h[k], W2[k * BIG + j], t);
        g[j] = fmaxf(t, 0.0f);
    }
    float u0 = b3[0], u1 = b3[1], u2 = b3[2], u3 = b3[3];
    #pragma unroll
    for (int k = 0; k < BIG; ++k) {
        u0 = fmaf(g[k], W3[k * DD + 0], u0);
        u1 = fmaf(g[k], W3[k * DD + 1], u1);
        u2 = fmaf(g[k], W3[k * DD + 2], u2);
        u3 = fmaf(g[k], W3[k * DD + 3], u3);
    }
    atomicAdd(&out[di * DD + 0], u0);
    atomicAdd(&out[di * DD + 1], u1);
    atomicAdd(&out[di * DD + 2], u2);
    atomicAdd(&out[di * DD + 3], u3);
}

__global__ void finalize_out_kernel(float* __restrict__ out, const float* __restrict__ cnt, int n)
{
    int i = blockIdx.x * blockDim.x + threadIdx.x;
    if (i >= n) return;
    float inv = 1.0f / fmaxf(cnt[i], 1.0f);
    float4 v = reinterpret_cast<float4*>(out)[i];
    v.x *= inv; v.y *= inv; v.z *= inv; v.w *= inv;
    reinterpret_cast<float4*>(out)[i] = v;
}

// ---------------- launch ----------------
extern "C" void kernel_launch(void* const* d_in, const int* in_sizes, int n_in,
                              void* d_out, int out_size, void* d_ws, size_t ws_size,
                              hipStream_t stream)
{
    const float* x     = (const float*)d_in[0];
    const int*   src   = (const int*)  d_in[1];
    const int*   dst   = (const int*)  d_in[2];
    const float* gamma = (const float*)d_in[3];
    const float* beta  = (const float*)d_in[4];
    const float* eW1 = (const float*)d_in[5];  const float* eb1 = (const float*)d_in[6];
    const float* eW2 = (const float*)d_in[7];  const float* eb2 = (const float*)d_in[8];
    const float* eW3 = (const float*)d_in[9];  const float* eb3 = (const float*)d_in[10];
    const float* dW1 = (const float*)d_in[11]; const float* db1 = (const float*)d_in[12];
    const float* dW2 = (const float*)d_in[13]; const float* db2 = (const float*)d_in[14];
    const float* dW3 = (const float*)d_in[15]; const float* db3 = (const float*)d_in[16];

    const int N = in_sizes[0] / DD;
    const int E = in_sizes[1];
    float* out = (float*)d_out;

    // Workspace (~65.7 MB at N=100k, E=3.2M — same budget as proven rounds).
    // Region A (E*8 bytes) time-multiplexed: {rank E*2, u E*4} until
    // scatter_srcu completes, then vs (E*8) from dec_mfma on.
    auto rnd16 = [](size_t b) { return (b + 15) & ~(size_t)15; };
    size_t need = 0;
    size_t o_sums  = need; need += rnd16(8 * 4);
    size_t o_ab    = need; need += rnd16(8 * 4);
    size_t o_bsum  = need; need += rnd16(256 * 4);
    size_t o_bbase = need; need += rnd16(256 * 4);
    size_t o_deg   = need; need += rnd16((size_t)N * 4);
    size_t o_off   = need; need += rnd16((size_t)(N + 1) * 4);
    size_t o_h1    = need; need += rnd16((size_t)2 * N * 4);
    size_t o_srcu  = need; need += rnd16((size_t)E * 8);   // {src, u(half2)} per slot
    size_t o_dsts  = need; need += rnd16((size_t)E * 4);   // dst per slot (by enc_reduce)
    size_t o_A     = need; need += rnd16((size_t)E * 8);   // rank(E*2)+u(E*4) -> vs(E*8)

    char* wsb = (char*)d_ws;

    if (ws_size >= need && N > 0 && E > 0) {
        float*          sums  = (float*)(wsb + o_sums);
        float*          ab    = (float*)(wsb + o_ab);
        int*            bsum  = (int*)  (wsb + o_bsum);
        int*            bbase = (int*)  (wsb + o_bbase);
        int*            deg   = (int*)  (wsb + o_deg);
        int*            off   = (int*)  (wsb + o_off);
        float*          h1    = (float*)(wsb + o_h1);
        uint2*          srcu  = (uint2*)(wsb + o_srcu);
        int*            dsts  = (int*)  (wsb + o_dsts);
        unsigned short* rank  = (unsigned short*)(wsb + o_A);
        u32*            u     = (u32*)  (wsb + o_A + rnd16((size_t)E * 2));
        uint2*          vs    = (uint2*)(wsb + o_A);

        hipMemsetAsync(sums, 0, 8 * sizeof(float), stream);
        hipMemsetAsync(deg, 0, (size_t)N * sizeof(int), stream);

        bn_reduce_kernel<<<256, 256, 0, stream>>>(x, N, sums);
        bn_finalize_kernel<<<1, 64, 0, stream>>>(sums, gamma, beta, ab, 1.0f / (float)N);

        int eblocks = (E + 255) / 256;
        int nbatch = (E + 15) / 16;
        int enc_blocks = 1024;              // measured optimum for the atomic pass
        int dec_blocks = 2048;              // no atomics: TLP helps

        // fused: MLP (MFMA) + rank histogram + u (half2) store
        enc_mfma_rank_kernel<<<enc_blocks, 256, 0, stream>>>(x, src, dst, ab,
                                                             eW1, eb1, eW2, eb2, eW3, eb3,
                                                             u, deg, rank, N, E,
                                                             nbatch, enc_blocks * 4);

        int nb = (N + SCAN_CHUNK - 1) / SCAN_CHUNK;
        scan_block_sums_kernel<<<nb, 256, 0, stream>>>(deg, N, bsum);
        scan_base_kernel<<<1, 64, 0, stream>>>(bsum, nb, bbase);
        scan_write_kernel<<<nb, 256, 0, stream>>>(deg, N, bbase, off);

        // single 8B scattered write per edge; rank & u dead after (region A -> vs)
        scatter_srcu_kernel<<<eblocks, 256, 0, stream>>>(src, dst, rank, off, u, srcu, E);

        int rblocks = ((N * 16) + 255) / 256;
        enc_reduce16_kernel<<<rblocks, 256, 0, stream>>>(srcu, off, h1, dsts, N);

        dec_mfma_kernel<<<dec_blocks, 256, 0, stream>>>(h1, srcu, dsts,
                                                        dW1, db1, dW2, db2, dW3, db3,
                                                        vs, N, E, nbatch, dec_blocks * 4);
        dec_reduce16_kernel<<<rblocks, 256, 0, stream>>>(vs, off, out, N);
    } else {
        float* ws   = (float*)d_ws;
        float* sums = ws;
        float* ab   = ws + 8;
        float* cnt  = ws + 16;
        float* acc1 = ws + 16 + N;

        hipMemsetAsync(sums, 0, 16 * sizeof(float), stream);
        hipMemsetAsync(cnt, 0, (size_t)(3 * N) * sizeof(float), stream);
        hipMemsetAsync(out, 0, (size_t)out_size * sizeof(float), stream);

        bn_reduce_kernel<<<256, 256, 0, stream>>>(x, N, sums);
        bn_finalize_kernel<<<1, 64, 0, stream>>>(sums, gamma, beta, ab, 1.0f / (float)N);

        int eblocks = (E + 255) / 256;
        enc_edge_kernel<<<eblocks, 256, 0, stream>>>(x, src, dst, ab,
                                                     eW1, eb1, eW2, eb2, eW3, eb3,
                                                     acc1, cnt, E);
        finalize_h1_kernel<<<(N + 255) / 256, 256, 0, stream>>>(acc1, cnt, N);
        dec_edge_kernel<<<eblocks, 256, 0, stream>>>(acc1, src, dst,
                                                     dW1, db1, dW2, db2, dW3, db3,
                                                     out, E);
        finalize_out_kernel<<<(N + 255) / 256, 256, 0, stream>>>(out, cnt, N);
    }
}